// Round 1
// baseline (2718.627 us; speedup 1.0000x reference)
//
#include <hip/hip_runtime.h>
#include <float.h>
#include <math.h>

#define N_ 8192
#define C_ 512
#define H_ 128

// ---------------- helpers ----------------
__device__ __forceinline__ float bred_sum128(float v, float* buf) {
  int t = threadIdx.x;
  buf[t] = v; __syncthreads();
  for (int s = 64; s > 0; s >>= 1) {
    if (t < s) buf[t] += buf[t + s];
    __syncthreads();
  }
  float r = buf[0]; __syncthreads();
  return r;
}

__device__ __forceinline__ void top3_ins(float (&tv)[3], int (&ti)[3], float v, int j) {
  bool b2 = (v > tv[2]) || (v == tv[2] && j < ti[2]);
  if (!b2) return;
  bool b1 = (v > tv[1]) || (v == tv[1] && j < ti[1]);
  if (b1) {
    tv[2] = tv[1]; ti[2] = ti[1];
    bool b0 = (v > tv[0]) || (v == tv[0] && j < ti[0]);
    if (b0) { tv[1] = tv[0]; ti[1] = ti[0]; tv[0] = v; ti[0] = j; }
    else    { tv[1] = v;     ti[1] = j; }
  } else { tv[2] = v; ti[2] = j; }
}

// ---------------- stage 1: concept aggregation ----------------
__global__ __launch_bounds__(256) void k_colsum1(const int* __restrict__ cm,
      const float* __restrict__ mv, float* __restrict__ colsum1) {
  int t = threadIdx.x;
  int c = blockIdx.x * 256 + t;
  int r0 = blockIdx.y * 256;
  float acc = 0.f;
  for (int r = 0; r < 256; ++r) {
    int i = r0 + r;
    acc += (float)cm[(size_t)i * C_ + c] * mv[i];
  }
  atomicAdd(&colsum1[c], acc);
}

// MODE 0: w = cm ? mv : 0   (hidden1 raw)
// MODE 1: w = exp(S - colmax)  (hidden2 raw, softmax numerator)
template<int MODE>
__global__ __launch_bounds__(256) void k_agg(const float* __restrict__ x,
      const int* __restrict__ cm, const float* __restrict__ mv,
      const float* __restrict__ S, const float* __restrict__ colmax,
      float* __restrict__ outCH) {
  __shared__ float ws[8][32];
  int t = threadIdx.x;
  int cbase = blockIdx.x * 32;
  int h = t & 127, half = t >> 7;
  float acc[16];
#pragma unroll
  for (int k = 0; k < 16; ++k) acc[k] = 0.f;
  int sr = t >> 5, sc = t & 31;
  for (int sub = 0; sub < 128; ++sub) {
    int ibase = blockIdx.y * 1024 + sub * 8;
    {
      int i = ibase + sr, c = cbase + sc;
      float w;
      if (MODE == 0) w = cm[(size_t)i * C_ + c] ? mv[i] : 0.f;
      else           w = expf(S[(size_t)i * C_ + c] - colmax[c]);
      ws[sr][sc] = w;
    }
    __syncthreads();
#pragma unroll
    for (int r = 0; r < 8; ++r) {
      float xv = x[(size_t)(ibase + r) * H_ + h];
      const float* wr = &ws[r][half * 16];
#pragma unroll
      for (int k = 0; k < 16; ++k) acc[k] += wr[k] * xv;
    }
    __syncthreads();
  }
#pragma unroll
  for (int k = 0; k < 16; ++k)
    atomicAdd(&outCH[(size_t)(cbase + half * 16 + k) * H_ + h], acc[k]);
}

__global__ __launch_bounds__(128) void k_fin_hidden1(float* __restrict__ h1,
      const float* __restrict__ colsum1, int* __restrict__ keep1) {
  __shared__ float buf[128];
  int c = blockIdx.x, t = threadIdx.x;
  float v = h1[(size_t)c * H_ + t] / (colsum1[c] + 1.f);
  h1[(size_t)c * H_ + t] = v;
  float sm = bred_sum128(v, buf);
  if (t == 0) keep1[c] = (sm != 0.f) ? 1 : 0;
}

__global__ __launch_bounds__(128) void k_fin_hidden2(float* __restrict__ h2,
      const float* __restrict__ colsumexp, float* __restrict__ rny) {
  __shared__ float buf[128];
  int c = blockIdx.x, t = threadIdx.x;
  float v = h2[(size_t)c * H_ + t] / colsumexp[c];
  h2[(size_t)c * H_ + t] = v;
  float ss = bred_sum128(v * v, buf);
  if (t == 0) rny[c] = (ss > 0.f) ? 1.f / sqrtf(ss) : 0.f;
}

__global__ __launch_bounds__(128) void k_rowstats(const float* __restrict__ A,
      float* __restrict__ rinv, float* __restrict__ diag, int* __restrict__ keep) {
  __shared__ float buf[128];
  int i = blockIdx.x, t = threadIdx.x;
  float v = A[(size_t)i * H_ + t];
  float ss = bred_sum128(v * v, buf);
  float sm = bred_sum128(v, buf);
  if (t == 0) {
    float nr = sqrtf(ss);
    if (rinv) rinv[i] = (ss > 0.f) ? 1.f / nr : 0.f;
    if (diag) diag[i] = (ss > 0.f) ? ss / (nr * nr) : 0.f;
    if (keep) keep[i] = (sm != 0.f) ? 1 : 0;
  }
}

// ---------------- generic fp32 tiled GEMM ----------------
// C[M,Nn] = A[M,K] @ B  (TRANSB: B is [Nn,K] row-major, else [K,Nn])
// epilogue: v = acc * rowscale[row] * colscale[col] + bias[col]; ACT=1 -> leaky_relu 0.01
template<int TRANSB, int ACT>
__global__ __launch_bounds__(256) void k_gemm(const float* __restrict__ A, int lda,
      const float* __restrict__ B, int ldb, float* __restrict__ Cc, int ldc,
      int M, int Nn, int Kk, const float* __restrict__ bias,
      const float* __restrict__ rowscale, const float* __restrict__ colscale) {
  __shared__ float As[16][68];
  __shared__ float Bs[16][68];
  int t = threadIdx.x;
  int n0 = blockIdx.x * 64, m0 = blockIdx.y * 64;
  int ty = t >> 4, tx = t & 15;
  float acc[4][4] = {};
  for (int k0 = 0; k0 < Kk; k0 += 16) {
#pragma unroll
    for (int li = t; li < 1024; li += 256) {
      int r = li >> 4, c = li & 15;
      As[c][r] = A[(size_t)(m0 + r) * lda + k0 + c];
    }
    if (TRANSB) {
#pragma unroll
      for (int li = t; li < 1024; li += 256) {
        int r = li >> 4, c = li & 15;
        Bs[c][r] = B[(size_t)(n0 + r) * ldb + k0 + c];
      }
    } else {
#pragma unroll
      for (int li = t; li < 1024; li += 256) {
        int nn = li & 63, c = li >> 6;
        Bs[c][nn] = B[(size_t)(k0 + c) * ldb + n0 + nn];
      }
    }
    __syncthreads();
#pragma unroll
    for (int kk = 0; kk < 16; ++kk) {
      float4 av = *(const float4*)&As[kk][ty * 4];
      float4 bv = *(const float4*)&Bs[kk][tx * 4];
      float a0 = av.x, a1 = av.y, a2 = av.z, a3 = av.w;
      float b0 = bv.x, b1 = bv.y, b2 = bv.z, b3 = bv.w;
      acc[0][0] += a0 * b0; acc[0][1] += a0 * b1; acc[0][2] += a0 * b2; acc[0][3] += a0 * b3;
      acc[1][0] += a1 * b0; acc[1][1] += a1 * b1; acc[1][2] += a1 * b2; acc[1][3] += a1 * b3;
      acc[2][0] += a2 * b0; acc[2][1] += a2 * b1; acc[2][2] += a2 * b2; acc[2][3] += a2 * b3;
      acc[3][0] += a3 * b0; acc[3][1] += a3 * b1; acc[3][2] += a3 * b2; acc[3][3] += a3 * b3;
    }
    __syncthreads();
  }
#pragma unroll
  for (int ii = 0; ii < 4; ++ii) {
    int row = m0 + ty * 4 + ii;
    float rs = rowscale ? rowscale[row] : 1.f;
#pragma unroll
    for (int jj = 0; jj < 4; ++jj) {
      int col = n0 + tx * 4 + jj;
      float v = acc[ii][jj] * rs;
      if (colscale) v *= colscale[col];
      if (bias) v += bias[col];
      if (ACT) v = (v > 0.f) ? v : 0.01f * v;
      Cc[(size_t)row * ldc + col] = v;
    }
  }
}

// ---------------- column softmax over S[N,C] ----------------
__global__ __launch_bounds__(256) void k_colmax_part(const float* __restrict__ S,
      float* __restrict__ part) {
  int t = threadIdx.x, b = blockIdx.x;
  int r0 = b * 256;
  float m0 = -FLT_MAX, m1 = -FLT_MAX;
  for (int r = 0; r < 256; ++r) {
    const float* row = S + (size_t)(r0 + r) * C_;
    m0 = fmaxf(m0, row[t]);
    m1 = fmaxf(m1, row[t + 256]);
  }
  part[(size_t)b * C_ + t] = m0;
  part[(size_t)b * C_ + t + 256] = m1;
}

__global__ __launch_bounds__(256) void k_colsum_part(const float* __restrict__ S,
      const float* __restrict__ colmax, float* __restrict__ part) {
  int t = threadIdx.x, b = blockIdx.x;
  int r0 = b * 256;
  float cm0 = colmax[t], cm1 = colmax[t + 256];
  float s0 = 0.f, s1 = 0.f;
  for (int r = 0; r < 256; ++r) {
    const float* row = S + (size_t)(r0 + r) * C_;
    s0 += expf(row[t] - cm0);
    s1 += expf(row[t + 256] - cm1);
  }
  part[(size_t)b * C_ + t] = s0;
  part[(size_t)b * C_ + t + 256] = s1;
}

__global__ __launch_bounds__(512) void k_colfin_max(const float* __restrict__ part,
      float* __restrict__ outv) {
  int c = threadIdx.x;
  float m = -FLT_MAX;
  for (int b = 0; b < 32; ++b) m = fmaxf(m, part[(size_t)b * C_ + c]);
  outv[c] = m;
}

__global__ __launch_bounds__(512) void k_colfin_sum(const float* __restrict__ part,
      float* __restrict__ outv) {
  int c = threadIdx.x;
  float s = 0.f;
  for (int b = 0; b < 32; ++b) s += part[(size_t)b * C_ + c];
  outv[c] = s;
}

// ---------------- row softmax (512 cols) with keep mask ----------------
__global__ __launch_bounds__(256) void k_rowsoftmax(float* __restrict__ Sm,
      const int* __restrict__ keep1) {
  __shared__ float buf[256];
  int i = blockIdx.x, t = threadIdx.x;
  float* row = Sm + (size_t)i * C_;
  int k0 = keep1[t], k1 = keep1[t + 256];
  float v0 = k0 ? row[t] : -FLT_MAX;
  float v1 = k1 ? row[t + 256] : -FLT_MAX;
  buf[t] = fmaxf(v0, v1); __syncthreads();
  for (int s = 128; s > 0; s >>= 1) {
    if (t < s) buf[t] = fmaxf(buf[t], buf[t + s]);
    __syncthreads();
  }
  float m = buf[0]; __syncthreads();
  float e0 = k0 ? expf(v0 - m) : 0.f;
  float e1 = k1 ? expf(v1 - m) : 0.f;
  buf[t] = e0 + e1; __syncthreads();
  for (int s = 128; s > 0; s >>= 1) {
    if (t < s) buf[t] += buf[t + s];
    __syncthreads();
  }
  float inv = 1.f / buf[0];
  row[t] = e0 * inv;
  row[t + 256] = e1 * inv;
}

// ---------------- N x N cosine Gram + top-3 (never materialized) ----------------
#define GI 32
#define GJ 64
__global__ __launch_bounds__(256) void k_gram_top3(const float* __restrict__ hs,
      const float* __restrict__ rn, float* __restrict__ gvals, int* __restrict__ gidx) {
  __shared__ float Qs[GI][H_ + 4];
  __shared__ float Js[GJ][H_ + 4];
  __shared__ float rqs[GI], rjs[GJ];
  __shared__ float mv_s[GI][16][3];
  __shared__ int   mi_s[GI][16][3];
  int t = threadIdx.x;
  int i0 = blockIdx.x * GI;
  for (int li = t; li < GI * H_; li += 256) {
    int r = li >> 7, c = li & 127;
    Qs[r][c] = hs[(size_t)(i0 + r) * H_ + c];
  }
  if (t < GI) rqs[t] = rn[i0 + t];
  int ty = t >> 4, tx = t & 15;
  float tv[2][3]; int ti[2][3];
#pragma unroll
  for (int q = 0; q < 2; ++q)
#pragma unroll
    for (int s = 0; s < 3; ++s) { tv[q][s] = -FLT_MAX; ti[q][s] = 0x7fffffff; }
  __syncthreads();
  for (int jt = 0; jt < N_ / GJ; ++jt) {
    int j0 = jt * GJ;
    for (int li = t; li < GJ * H_; li += 256) {
      int r = li >> 7, c = li & 127;
      Js[r][c] = hs[(size_t)(j0 + r) * H_ + c];
    }
    if (t < GJ) rjs[t] = rn[j0 + t];
    __syncthreads();
    float acc[2][4] = {{0.f,0.f,0.f,0.f},{0.f,0.f,0.f,0.f}};
    for (int k = 0; k < H_; k += 4) {
      float4 a0 = *(const float4*)&Qs[ty * 2 + 0][k];
      float4 a1 = *(const float4*)&Qs[ty * 2 + 1][k];
#pragma unroll
      for (int jj = 0; jj < 4; ++jj) {
        float4 b = *(const float4*)&Js[jj * 16 + tx][k];
        acc[0][jj] += a0.x * b.x + a0.y * b.y + a0.z * b.z + a0.w * b.w;
        acc[1][jj] += a1.x * b.x + a1.y * b.y + a1.z * b.z + a1.w * b.w;
      }
    }
#pragma unroll
    for (int q = 0; q < 2; ++q) {
      int gi = i0 + ty * 2 + q;
      float rq = rqs[ty * 2 + q];
#pragma unroll
      for (int jj = 0; jj < 4; ++jj) {
        int jl = jj * 16 + tx;
        int j = j0 + jl;
        float v = (j == gi) ? 0.f : acc[q][jj] * rq * rjs[jl];
        top3_ins(tv[q], ti[q], v, j);
      }
    }
    __syncthreads();
  }
#pragma unroll
  for (int q = 0; q < 2; ++q) {
    int r = ty * 2 + q;
#pragma unroll
    for (int s = 0; s < 3; ++s) { mv_s[r][tx][s] = tv[q][s]; mi_s[r][tx][s] = ti[q][s]; }
  }
  __syncthreads();
  if (t < GI) {
    float bv[3] = {-FLT_MAX, -FLT_MAX, -FLT_MAX};
    int bi[3] = {0x7fffffff, 0x7fffffff, 0x7fffffff};
    for (int u = 0; u < 16; ++u)
#pragma unroll
      for (int s = 0; s < 3; ++s) top3_ins(bv, bi, mv_s[t][u][s], mi_s[t][u][s]);
#pragma unroll
    for (int s = 0; s < 3; ++s) {
      gvals[(size_t)(i0 + t) * 3 + s] = bv[s];
      gidx[(size_t)(i0 + t) * 3 + s] = bi[s];
    }
  }
}

// ---------------- sparse scatter: hidden3 = hs2c^T @ h_shared ----------------
__global__ __launch_bounds__(128) void k_scatter(const float* __restrict__ hs,
      const float* __restrict__ gvals, const int* __restrict__ gidx,
      float* __restrict__ hidden3, float* __restrict__ colsum3) {
  int i = blockIdx.x, t = threadIdx.x;
  float xs = hs[(size_t)i * H_ + t];
#pragma unroll
  for (int k = 0; k < 3; ++k) {
    int j = gidx[i * 3 + k];
    float v = gvals[i * 3 + k];
    atomicAdd(&hidden3[(size_t)j * H_ + t], v * xs);
  }
  if (t == 0) {
#pragma unroll
    for (int k = 0; k < 3; ++k) atomicAdd(&colsum3[gidx[i * 3 + k]], gvals[i * 3 + k]);
  }
}

__global__ __launch_bounds__(128) void k_h3fin(float* __restrict__ hidden3,
      const float* __restrict__ hs, const float* __restrict__ colsum3,
      const float* __restrict__ diagv, float* __restrict__ rn3, int* __restrict__ keep2) {
  __shared__ float buf[128];
  int j = blockIdx.x, t = threadIdx.x;
  float v = hidden3[(size_t)j * H_ + t];
  if (colsum3[j] != 0.f) v += diagv[j] * hs[(size_t)j * H_ + t];
  hidden3[(size_t)j * H_ + t] = v;
  float ss = bred_sum128(v * v, buf);
  float sm = bred_sum128(v, buf);
  if (t == 0) {
    rn3[j] = (ss > 0.f) ? 1.f / sqrtf(ss) : 0.f;
    keep2[j] = (sm != 0.f) ? 1 : 0;
  }
}

// ---------------- online-softmax cosine attention: out = softmax(cos(hs, h3)) @ h3 ----
#define AQ 32
#define AJ 64
__global__ __launch_bounds__(256) void k_attn(const float* __restrict__ Q,
      const float* __restrict__ rq_, const float* __restrict__ KV,
      const float* __restrict__ rj_, const int* __restrict__ kp_,
      float* __restrict__ outp) {
  __shared__ float Qs[AQ][H_ + 4];
  __shared__ float Js[AJ][H_ + 4];
  __shared__ float Sc[AQ][AJ];
  __shared__ float rqs[AQ], m_s[AQ], l_s[AQ], al_s[AQ];
  __shared__ float rjs[AJ];
  __shared__ int kps[AJ];
  __shared__ float pm[AQ][8];
  int t = threadIdx.x;
  int i0 = blockIdx.x * AQ;
  for (int li = t; li < AQ * H_; li += 256) {
    int r = li >> 7, c = li & 127;
    Qs[r][c] = Q[(size_t)(i0 + r) * H_ + c];
  }
  if (t < AQ) { rqs[t] = rq_[i0 + t]; m_s[t] = -FLT_MAX; l_s[t] = 0.f; }
  int ty = t >> 4, tx = t & 15;
  int rg = t >> 4, hg = t & 15;
  float O[2][8];
#pragma unroll
  for (int a = 0; a < 2; ++a)
#pragma unroll
    for (int b = 0; b < 8; ++b) O[a][b] = 0.f;
  __syncthreads();
  for (int jt = 0; jt < N_ / AJ; ++jt) {
    int j0 = jt * AJ;
    for (int li = t; li < AJ * H_; li += 256) {
      int r = li >> 7, c = li & 127;
      Js[r][c] = KV[(size_t)(j0 + r) * H_ + c];
    }
    if (t < AJ) { rjs[t] = rj_[j0 + t]; kps[t] = kp_[j0 + t]; }
    __syncthreads();
    // phase A: scores
    {
      float acc[2][4] = {{0.f,0.f,0.f,0.f},{0.f,0.f,0.f,0.f}};
      for (int k = 0; k < H_; k += 4) {
        float4 a0 = *(const float4*)&Qs[ty * 2 + 0][k];
        float4 a1 = *(const float4*)&Qs[ty * 2 + 1][k];
#pragma unroll
        for (int jj = 0; jj < 4; ++jj) {
          float4 b = *(const float4*)&Js[jj * 16 + tx][k];
          acc[0][jj] += a0.x * b.x + a0.y * b.y + a0.z * b.z + a0.w * b.w;
          acc[1][jj] += a1.x * b.x + a1.y * b.y + a1.z * b.z + a1.w * b.w;
        }
      }
#pragma unroll
      for (int q = 0; q < 2; ++q) {
        int qr = ty * 2 + q;
#pragma unroll
        for (int jj = 0; jj < 4; ++jj) {
          int jl = jj * 16 + tx;
          float v = kps[jl] ? acc[q][jj] * rqs[qr] * rjs[jl] : -FLT_MAX;
          Sc[qr][jl] = v;
        }
      }
    }
    __syncthreads();
    // B1 partial max
    {
      int r = t >> 3, sg = t & 7;
      float mm = -FLT_MAX;
#pragma unroll
      for (int u = 0; u < 8; ++u) mm = fmaxf(mm, Sc[r][sg * 8 + u]);
      pm[r][sg] = mm;
    }
    __syncthreads();
    // B2 running max + alpha
    if (t < AQ) {
      float nm = m_s[t];
#pragma unroll
      for (int u = 0; u < 8; ++u) nm = fmaxf(nm, pm[t][u]);
      float al = (nm == -FLT_MAX) ? 1.f : expf(m_s[t] - nm);
      al_s[t] = al; m_s[t] = nm;
    }
    __syncthreads();
    // B3 exponentiate in place
    {
      int r = t >> 3, sg = t & 7;
      float m = m_s[r];
      float ssum = 0.f;
#pragma unroll
      for (int u = 0; u < 8; ++u) {
        int j = sg * 8 + u;
        float v = Sc[r][j];
        float e = kps[j] ? expf(v - m) : 0.f;
        Sc[r][j] = e;
        ssum += e;
      }
      pm[r][sg] = ssum;
    }
    __syncthreads();
    // B4: l update (t<AQ) + phase C: O update (all threads)
    if (t < AQ) {
      float s = 0.f;
#pragma unroll
      for (int u = 0; u < 8; ++u) s += pm[t][u];
      l_s[t] = l_s[t] * al_s[t] + s;
    }
    {
      int r0 = rg * 2, r1 = rg * 2 + 1;
      float a0 = al_s[r0], a1 = al_s[r1];
#pragma unroll
      for (int u = 0; u < 8; ++u) { O[0][u] *= a0; O[1][u] *= a1; }
      for (int jj = 0; jj < AJ; jj += 4) {
        float4 e0 = *(const float4*)&Sc[r0][jj];
        float4 e1 = *(const float4*)&Sc[r1][jj];
        float e0a[4] = {e0.x, e0.y, e0.z, e0.w};
        float e1a[4] = {e1.x, e1.y, e1.z, e1.w};
#pragma unroll
        for (int v4 = 0; v4 < 4; ++v4) {
          int j = jj + v4;
          float4 J0 = *(const float4*)&Js[j][hg * 8];
          float4 J1 = *(const float4*)&Js[j][hg * 8 + 4];
          float ev0 = e0a[v4], ev1 = e1a[v4];
          O[0][0] += ev0 * J0.x; O[0][1] += ev0 * J0.y; O[0][2] += ev0 * J0.z; O[0][3] += ev0 * J0.w;
          O[0][4] += ev0 * J1.x; O[0][5] += ev0 * J1.y; O[0][6] += ev0 * J1.z; O[0][7] += ev0 * J1.w;
          O[1][0] += ev1 * J0.x; O[1][1] += ev1 * J0.y; O[1][2] += ev1 * J0.z; O[1][3] += ev1 * J0.w;
          O[1][4] += ev1 * J1.x; O[1][5] += ev1 * J1.y; O[1][6] += ev1 * J1.z; O[1][7] += ev1 * J1.w;
        }
      }
    }
    __syncthreads();
  }
  {
    int r0 = rg * 2, r1 = rg * 2 + 1;
    float l0 = l_s[r0], l1 = l_s[r1];
    float i0v = (l0 > 0.f) ? 1.f / l0 : 0.f;
    float i1v = (l1 > 0.f) ? 1.f / l1 : 0.f;
#pragma unroll
    for (int u = 0; u < 8; ++u) {
      outp[(size_t)(i0 + r0) * H_ + hg * 8 + u] = O[0][u] * i0v;
      outp[(size_t)(i0 + r1) * H_ + hg * 8 + u] = O[1][u] * i1v;
    }
  }
}

// ---------------- elementwise ----------------
__global__ __launch_bounds__(256) void k_sub2(const float4* __restrict__ a,
      const float4* __restrict__ b, float4* __restrict__ o) {
  int i = blockIdx.x * 256 + threadIdx.x;
  float4 x = a[i], y = b[i], r;
  r.x = x.x - y.x; r.y = x.y - y.y; r.z = x.z - y.z; r.w = x.w - y.w;
  o[i] = r;
}

__global__ __launch_bounds__(256) void k_sub3(const float4* __restrict__ a,
      const float4* __restrict__ b, const float4* __restrict__ c, float4* __restrict__ o) {
  int i = blockIdx.x * 256 + threadIdx.x;
  float4 x = a[i], y = b[i], z = c[i], r;
  r.x = x.x - y.x - z.x; r.y = x.y - y.y - z.y; r.z = x.z - y.z - z.z; r.w = x.w - y.w - z.w;
  o[i] = r;
}

__global__ __launch_bounds__(128) void k_pred(const float* __restrict__ a,
      const float* __restrict__ b, const float* __restrict__ c,
      const float* __restrict__ wout, const float* __restrict__ bout,
      float* __restrict__ outp) {
  __shared__ float buf[128];
  int i = blockIdx.x, t = threadIdx.x;
  size_t idx = (size_t)i * H_ + t;
  float v = (a[idx] + b[idx] + c[idx]) * wout[t];
  float s = bred_sum128(v, buf);
  if (t == 0) outp[i] = s + bout[0];
}

// ---------------- host ----------------
extern "C" void kernel_launch(void* const* d_in, const int* in_sizes, int n_in,
                              void* d_out, int out_size, void* d_ws, size_t ws_size,
                              hipStream_t stream) {
  const float* x          = (const float*)d_in[0];
  const float* mv         = (const float*)d_in[1];
  const int*   cm         = (const int*)d_in[2];
  const float* W_ps       = (const float*)d_in[3];
  const float* b_ps       = (const float*)d_in[4];
  const float* W_hs       = (const float*)d_in[5];
  const float* b_hs       = (const float*)d_in[6];
  const float* W_ps_fore  = (const float*)d_in[7];
  const float* b_ps_fore  = (const float*)d_in[8];
  const float* W_hs_fore  = (const float*)d_in[9];
  const float* b_hs_fore  = (const float*)d_in[10];
  const float* W_ps_back  = (const float*)d_in[11];
  const float* b_ps_back  = (const float*)d_in[12];
  const float* W_hs_back  = (const float*)d_in[13];
  const float* b_hs_back  = (const float*)d_in[14];
  const float* W_indi     = (const float*)d_in[15];
  const float* b_indi     = (const float*)d_in[16];
  const float* W_out      = (const float*)d_in[23];
  const float* b_out      = (const float*)d_in[24];
  float* outp = (float*)d_out;

  float* W = (float*)d_ws;
  const size_t NC = (size_t)N_ * C_;
  const size_t NH = (size_t)N_ * H_;
  const size_t CH = (size_t)C_ * H_;
  float* Sbuf = W;
  // S region is free after T1 is produced; reuse it for 4 later [N,H] buffers
  float* pback   = Sbuf;
  float* outps   = Sbuf + NH;
  float* hback   = Sbuf + 2 * NH;
  float* outindi = Sbuf + 3 * NH;
  size_t off = NC;
  float* T1       = W + off; off += NH;   // also reused as attention output
  float* p_shared = W + off; off += NH;
  float* h_shared = W + off; off += NH;   // later reused for indiv
  float* hidden3  = W + off; off += NH;
  float* h_info   = W + off; off += NH;
  float* out_hs   = W + off; off += NH;
  float* hidden1  = W + off; off += CH;
  float* hidden2  = W + off; off += CH;
  float* colsum1   = W + off; off += C_;
  float* colmax    = W + off; off += C_;
  float* colsumexp = W + off; off += C_;
  float* rny2      = W + off; off += C_;
  float* partb     = W + off; off += 32 * C_;
  float* rnx     = W + off; off += N_;
  float* rqh     = W + off; off += N_;
  float* diagv   = W + off; off += N_;
  float* colsum3 = W + off; off += N_;
  float* rn3     = W + off; off += N_;
  float* gvals   = W + off; off += 3 * N_;
  int* keep1 = (int*)(W + off); off += C_;
  int* keep2 = (int*)(W + off); off += N_;
  int* gidx  = (int*)(W + off); off += 3 * N_;

  hipMemsetAsync(colsum1, 0, C_ * sizeof(float), stream);
  hipMemsetAsync(hidden1, 0, CH * sizeof(float), stream);
  hipMemsetAsync(hidden2, 0, CH * sizeof(float), stream);
  hipMemsetAsync(hidden3, 0, NH * sizeof(float), stream);
  hipMemsetAsync(colsum3, 0, N_ * sizeof(float), stream);

  // stage 1: market-value aggregation
  k_colsum1<<<dim3(2, 32), 256, 0, stream>>>(cm, mv, colsum1);
  k_agg<0><<<dim3(16, 8), 256, 0, stream>>>(x, cm, mv, nullptr, nullptr, hidden1);
  k_fin_hidden1<<<C_, 128, 0, stream>>>(hidden1, colsum1, keep1);
  k_rowstats<<<N_, 128, 0, stream>>>(x, rnx, nullptr, nullptr);

  // stage 2: softmax over stocks, hidden2
  k_gemm<1, 0><<<dim3(C_ / 64, N_ / 64), 256, 0, stream>>>(
      x, H_, hidden1, H_, Sbuf, C_, N_, C_, H_, nullptr, nullptr, nullptr);
  k_colmax_part<<<32, 256, 0, stream>>>(Sbuf, partb);
  k_colfin_max<<<1, 512, 0, stream>>>(partb, colmax);
  k_colsum_part<<<32, 256, 0, stream>>>(Sbuf, colmax, partb);
  k_colfin_sum<<<1, 512, 0, stream>>>(partb, colsumexp);
  k_agg<1><<<dim3(16, 8), 256, 0, stream>>>(x, nullptr, nullptr, Sbuf, colmax, hidden2);
  k_fin_hidden2<<<C_, 128, 0, stream>>>(hidden2, colsumexp, rny2);

  // stage 3: c2s = softmax(cos_sim(x, hidden2), axis=1 masked by keep1); p branch
  k_gemm<1, 0><<<dim3(C_ / 64, N_ / 64), 256, 0, stream>>>(
      x, H_, hidden2, H_, Sbuf, C_, N_, C_, H_, nullptr, rnx, rny2);
  k_rowsoftmax<<<N_, 256, 0, stream>>>(Sbuf, keep1);
  k_gemm<0, 0><<<dim3(H_ / 64, N_ / 64), 256, 0, stream>>>(
      Sbuf, C_, hidden2, H_, T1, H_, N_, H_, C_, nullptr, nullptr, nullptr);
  k_gemm<0, 0><<<dim3(2, 128), 256, 0, stream>>>(
      T1, H_, W_ps, H_, p_shared, H_, N_, H_, H_, b_ps, nullptr, nullptr);
  k_gemm<0, 0><<<dim3(2, 128), 256, 0, stream>>>(
      p_shared, H_, W_ps_back, H_, pback, H_, N_, H_, H_, b_ps_back, nullptr, nullptr);
  k_gemm<0, 1><<<dim3(2, 128), 256, 0, stream>>>(
      p_shared, H_, W_ps_fore, H_, outps, H_, N_, H_, H_, b_ps_fore, nullptr, nullptr);

  // stage 4: h_shared, N x N top-3 graph, sparse aggregation
  k_sub2<<<NH / 4 / 256, 256, 0, stream>>>((const float4*)x, (const float4*)pback,
                                           (float4*)h_shared);
  k_rowstats<<<N_, 128, 0, stream>>>(h_shared, rqh, diagv, nullptr);
  k_gram_top3<<<N_ / GI, 256, 0, stream>>>(h_shared, rqh, gvals, gidx);
  k_scatter<<<N_, 128, 0, stream>>>(h_shared, gvals, gidx, hidden3, colsum3);
  k_h3fin<<<N_, 128, 0, stream>>>(hidden3, h_shared, colsum3, diagv, rn3, keep2);

  // stage 5: dense cosine attention, h branch
  k_attn<<<N_ / AQ, 256, 0, stream>>>(h_shared, rqh, hidden3, rn3, keep2, T1);
  k_gemm<0, 0><<<dim3(2, 128), 256, 0, stream>>>(
      T1, H_, W_hs, H_, h_info, H_, N_, H_, H_, b_hs, nullptr, nullptr);
  k_gemm<0, 0><<<dim3(2, 128), 256, 0, stream>>>(
      h_info, H_, W_hs_back, H_, hback, H_, N_, H_, H_, b_hs_back, nullptr, nullptr);
  k_gemm<0, 1><<<dim3(2, 128), 256, 0, stream>>>(
      h_info, H_, W_hs_fore, H_, out_hs, H_, N_, H_, H_, b_hs_fore, nullptr, nullptr);

  // stage 6: individual branch + final projection
  k_sub3<<<NH / 4 / 256, 256, 0, stream>>>((const float4*)x, (const float4*)pback,
                                           (const float4*)hback, (float4*)h_shared);
  k_gemm<0, 1><<<dim3(2, 128), 256, 0, stream>>>(
      h_shared, H_, W_indi, H_, outindi, H_, N_, H_, H_, b_indi, nullptr, nullptr);
  k_pred<<<N_, 128, 0, stream>>>(outps, out_hs, outindi, W_out, b_out, outp);
}

// Round 3
// 1826.404 us; speedup vs baseline: 1.4885x; 1.4885x over previous
//
#include <hip/hip_runtime.h>
#include <float.h>
#include <math.h>

#define N_ 8192
#define C_ 512
#define H_ 128

typedef __attribute__((ext_vector_type(8))) short bfrag;
typedef __attribute__((ext_vector_type(4))) float f4;

__device__ __forceinline__ ushort f2bf(float f) {
  unsigned u = __float_as_uint(f);
  unsigned r = (u + 0x7fffu + ((u >> 16) & 1u)) >> 16;
  return (ushort)r;
}

// ---------------- helpers ----------------
__device__ __forceinline__ float bred_sum128(float v, float* buf) {
  int t = threadIdx.x;
  buf[t] = v; __syncthreads();
  for (int s = 64; s > 0; s >>= 1) {
    if (t < s) buf[t] += buf[t + s];
    __syncthreads();
  }
  float r = buf[0]; __syncthreads();
  return r;
}

__device__ __forceinline__ void top3_ins(float (&tv)[3], int (&ti)[3], float v, int j) {
  bool b2 = (v > tv[2]) || (v == tv[2] && j < ti[2]);
  if (!b2) return;
  bool b1 = (v > tv[1]) || (v == tv[1] && j < ti[1]);
  if (b1) {
    tv[2] = tv[1]; ti[2] = ti[1];
    bool b0 = (v > tv[0]) || (v == tv[0] && j < ti[0]);
    if (b0) { tv[1] = tv[0]; ti[1] = ti[0]; tv[0] = v; ti[0] = j; }
    else    { tv[1] = v;     ti[1] = j; }
  } else { tv[2] = v; ti[2] = j; }
}

// ---------------- stage 1: concept aggregation ----------------
__global__ __launch_bounds__(256) void k_colsum1(const int* __restrict__ cm,
      const float* __restrict__ mv, float* __restrict__ colsum1) {
  int t = threadIdx.x;
  int c = blockIdx.x * 256 + t;
  int r0 = blockIdx.y * 256;
  float acc = 0.f;
  for (int r = 0; r < 256; ++r) {
    int i = r0 + r;
    acc += (float)cm[(size_t)i * C_ + c] * mv[i];
  }
  atomicAdd(&colsum1[c], acc);
}

template<int MODE>
__global__ __launch_bounds__(256) void k_agg(const float* __restrict__ x,
      const int* __restrict__ cm, const float* __restrict__ mv,
      const float* __restrict__ S, const float* __restrict__ colmax,
      float* __restrict__ outCH) {
  __shared__ float ws[8][32];
  int t = threadIdx.x;
  int cbase = blockIdx.x * 32;
  int h = t & 127, half = t >> 7;
  float acc[16];
#pragma unroll
  for (int k = 0; k < 16; ++k) acc[k] = 0.f;
  int sr = t >> 5, sc = t & 31;
  for (int sub = 0; sub < 128; ++sub) {
    int ibase = blockIdx.y * 1024 + sub * 8;
    {
      int i = ibase + sr, c = cbase + sc;
      float w;
      if (MODE == 0) w = cm[(size_t)i * C_ + c] ? mv[i] : 0.f;
      else           w = expf(S[(size_t)i * C_ + c] - colmax[c]);
      ws[sr][sc] = w;
    }
    __syncthreads();
#pragma unroll
    for (int r = 0; r < 8; ++r) {
      float xv = x[(size_t)(ibase + r) * H_ + h];
      const float* wr = &ws[r][half * 16];
#pragma unroll
      for (int k = 0; k < 16; ++k) acc[k] += wr[k] * xv;
    }
    __syncthreads();
  }
#pragma unroll
  for (int k = 0; k < 16; ++k)
    atomicAdd(&outCH[(size_t)(cbase + half * 16 + k) * H_ + h], acc[k]);
}

__global__ __launch_bounds__(128) void k_fin_hidden1(float* __restrict__ h1,
      const float* __restrict__ colsum1, int* __restrict__ keep1) {
  __shared__ float buf[128];
  int c = blockIdx.x, t = threadIdx.x;
  float v = h1[(size_t)c * H_ + t] / (colsum1[c] + 1.f);
  h1[(size_t)c * H_ + t] = v;
  float sm = bred_sum128(v, buf);
  if (t == 0) keep1[c] = (sm != 0.f) ? 1 : 0;
}

__global__ __launch_bounds__(128) void k_fin_hidden2(float* __restrict__ h2,
      const float* __restrict__ colsumexp, float* __restrict__ rny) {
  __shared__ float buf[128];
  int c = blockIdx.x, t = threadIdx.x;
  float v = h2[(size_t)c * H_ + t] / colsumexp[c];
  h2[(size_t)c * H_ + t] = v;
  float ss = bred_sum128(v * v, buf);
  if (t == 0) rny[c] = (ss > 0.f) ? 1.f / sqrtf(ss) : 0.f;
}

__global__ __launch_bounds__(128) void k_rowstats(const float* __restrict__ A,
      float* __restrict__ rinv, float* __restrict__ diag, int* __restrict__ keep) {
  __shared__ float buf[128];
  int i = blockIdx.x, t = threadIdx.x;
  float v = A[(size_t)i * H_ + t];
  float ss = bred_sum128(v * v, buf);
  float sm = bred_sum128(v, buf);
  if (t == 0) {
    float nr = sqrtf(ss);
    if (rinv) rinv[i] = (ss > 0.f) ? 1.f / nr : 0.f;
    if (diag) diag[i] = (ss > 0.f) ? ss / (nr * nr) : 0.f;
    if (keep) keep[i] = (sm != 0.f) ? 1 : 0;
  }
}

// ---------------- generic fp32 tiled GEMM ----------------
template<int TRANSB, int ACT>
__global__ __launch_bounds__(256) void k_gemm(const float* __restrict__ A, int lda,
      const float* __restrict__ B, int ldb, float* __restrict__ Cc, int ldc,
      int M, int Nn, int Kk, const float* __restrict__ bias,
      const float* __restrict__ rowscale, const float* __restrict__ colscale) {
  __shared__ float As[16][68];
  __shared__ float Bs[16][68];
  int t = threadIdx.x;
  int n0 = blockIdx.x * 64, m0 = blockIdx.y * 64;
  int ty = t >> 4, tx = t & 15;
  float acc[4][4] = {};
  for (int k0 = 0; k0 < Kk; k0 += 16) {
#pragma unroll
    for (int li = t; li < 1024; li += 256) {
      int r = li >> 4, c = li & 15;
      As[c][r] = A[(size_t)(m0 + r) * lda + k0 + c];
    }
    if (TRANSB) {
#pragma unroll
      for (int li = t; li < 1024; li += 256) {
        int r = li >> 4, c = li & 15;
        Bs[c][r] = B[(size_t)(n0 + r) * ldb + k0 + c];
      }
    } else {
#pragma unroll
      for (int li = t; li < 1024; li += 256) {
        int nn = li & 63, c = li >> 6;
        Bs[c][nn] = B[(size_t)(k0 + c) * ldb + n0 + nn];
      }
    }
    __syncthreads();
#pragma unroll
    for (int kk = 0; kk < 16; ++kk) {
      float4 av = *(const float4*)&As[kk][ty * 4];
      float4 bv = *(const float4*)&Bs[kk][tx * 4];
      float a0 = av.x, a1 = av.y, a2 = av.z, a3 = av.w;
      float b0 = bv.x, b1 = bv.y, b2 = bv.z, b3 = bv.w;
      acc[0][0] += a0 * b0; acc[0][1] += a0 * b1; acc[0][2] += a0 * b2; acc[0][3] += a0 * b3;
      acc[1][0] += a1 * b0; acc[1][1] += a1 * b1; acc[1][2] += a1 * b2; acc[1][3] += a1 * b3;
      acc[2][0] += a2 * b0; acc[2][1] += a2 * b1; acc[2][2] += a2 * b2; acc[2][3] += a2 * b3;
      acc[3][0] += a3 * b0; acc[3][1] += a3 * b1; acc[3][2] += a3 * b2; acc[3][3] += a3 * b3;
    }
    __syncthreads();
  }
#pragma unroll
  for (int ii = 0; ii < 4; ++ii) {
    int row = m0 + ty * 4 + ii;
    float rs = rowscale ? rowscale[row] : 1.f;
#pragma unroll
    for (int jj = 0; jj < 4; ++jj) {
      int col = n0 + tx * 4 + jj;
      float v = acc[ii][jj] * rs;
      if (colscale) v *= colscale[col];
      if (bias) v += bias[col];
      if (ACT) v = (v > 0.f) ? v : 0.01f * v;
      Cc[(size_t)row * ldc + col] = v;
    }
  }
}

// ---------------- column softmax over S[N,C] ----------------
__global__ __launch_bounds__(256) void k_colmax_part(const float* __restrict__ S,
      float* __restrict__ part) {
  int t = threadIdx.x, b = blockIdx.x;
  int r0 = b * 256;
  float m0 = -FLT_MAX, m1 = -FLT_MAX;
  for (int r = 0; r < 256; ++r) {
    const float* row = S + (size_t)(r0 + r) * C_;
    m0 = fmaxf(m0, row[t]);
    m1 = fmaxf(m1, row[t + 256]);
  }
  part[(size_t)b * C_ + t] = m0;
  part[(size_t)b * C_ + t + 256] = m1;
}

__global__ __launch_bounds__(256) void k_colsum_part(const float* __restrict__ S,
      const float* __restrict__ colmax, float* __restrict__ part) {
  int t = threadIdx.x, b = blockIdx.x;
  int r0 = b * 256;
  float cm0 = colmax[t], cm1 = colmax[t + 256];
  float s0 = 0.f, s1 = 0.f;
  for (int r = 0; r < 256; ++r) {
    const float* row = S + (size_t)(r0 + r) * C_;
    s0 += expf(row[t] - cm0);
    s1 += expf(row[t + 256] - cm1);
  }
  part[(size_t)b * C_ + t] = s0;
  part[(size_t)b * C_ + t + 256] = s1;
}

__global__ __launch_bounds__(512) void k_colfin_max(const float* __restrict__ part,
      float* __restrict__ outv) {
  int c = threadIdx.x;
  float m = -FLT_MAX;
  for (int b = 0; b < 32; ++b) m = fmaxf(m, part[(size_t)b * C_ + c]);
  outv[c] = m;
}

__global__ __launch_bounds__(512) void k_colfin_sum(const float* __restrict__ part,
      float* __restrict__ outv) {
  int c = threadIdx.x;
  float s = 0.f;
  for (int b = 0; b < 32; ++b) s += part[(size_t)b * C_ + c];
  outv[c] = s;
}

// ---------------- row softmax (512 cols) with keep mask ----------------
__global__ __launch_bounds__(256) void k_rowsoftmax(float* __restrict__ Sm,
      const int* __restrict__ keep1) {
  __shared__ float buf[256];
  int i = blockIdx.x, t = threadIdx.x;
  float* row = Sm + (size_t)i * C_;
  int k0 = keep1[t], k1 = keep1[t + 256];
  float v0 = k0 ? row[t] : -FLT_MAX;
  float v1 = k1 ? row[t + 256] : -FLT_MAX;
  buf[t] = fmaxf(v0, v1); __syncthreads();
  for (int s = 128; s > 0; s >>= 1) {
    if (t < s) buf[t] = fmaxf(buf[t], buf[t + s]);
    __syncthreads();
  }
  float m = buf[0]; __syncthreads();
  float e0 = k0 ? expf(v0 - m) : 0.f;
  float e1 = k1 ? expf(v1 - m) : 0.f;
  buf[t] = e0 + e1; __syncthreads();
  for (int s = 128; s > 0; s >>= 1) {
    if (t < s) buf[t] += buf[t + s];
    __syncthreads();
  }
  float inv = 1.f / buf[0];
  row[t] = e0 * inv;
  row[t + 256] = e1 * inv;
}

// ---------------- N x N cosine Gram + top-3 (fp32, never materialized) ----------------
#define GI 32
#define GJ 64
__global__ __launch_bounds__(256) void k_gram_top3(const float* __restrict__ hs,
      const float* __restrict__ rn, float* __restrict__ gvals, int* __restrict__ gidx) {
  __shared__ float Qs[GI][H_ + 4];
  __shared__ float Js[GJ][H_ + 4];
  __shared__ float rqs[GI], rjs[GJ];
  __shared__ float mv_s[GI][16][3];
  __shared__ int   mi_s[GI][16][3];
  int t = threadIdx.x;
  int i0 = blockIdx.x * GI;
  for (int li = t; li < GI * H_; li += 256) {
    int r = li >> 7, c = li & 127;
    Qs[r][c] = hs[(size_t)(i0 + r) * H_ + c];
  }
  if (t < GI) rqs[t] = rn[i0 + t];
  int ty = t >> 4, tx = t & 15;
  float tv[2][3]; int ti[2][3];
#pragma unroll
  for (int q = 0; q < 2; ++q)
#pragma unroll
    for (int s = 0; s < 3; ++s) { tv[q][s] = -FLT_MAX; ti[q][s] = 0x7fffffff; }
  __syncthreads();
  for (int jt = 0; jt < N_ / GJ; ++jt) {
    int j0 = jt * GJ;
    for (int li = t; li < GJ * H_; li += 256) {
      int r = li >> 7, c = li & 127;
      Js[r][c] = hs[(size_t)(j0 + r) * H_ + c];
    }
    if (t < GJ) rjs[t] = rn[j0 + t];
    __syncthreads();
    float acc[2][4] = {{0.f,0.f,0.f,0.f},{0.f,0.f,0.f,0.f}};
    for (int k = 0; k < H_; k += 4) {
      float4 a0 = *(const float4*)&Qs[ty * 2 + 0][k];
      float4 a1 = *(const float4*)&Qs[ty * 2 + 1][k];
#pragma unroll
      for (int jj = 0; jj < 4; ++jj) {
        float4 b = *(const float4*)&Js[jj * 16 + tx][k];
        acc[0][jj] += a0.x * b.x + a0.y * b.y + a0.z * b.z + a0.w * b.w;
        acc[1][jj] += a1.x * b.x + a1.y * b.y + a1.z * b.z + a1.w * b.w;
      }
    }
#pragma unroll
    for (int q = 0; q < 2; ++q) {
      int gi = i0 + ty * 2 + q;
      float rq = rqs[ty * 2 + q];
#pragma unroll
      for (int jj = 0; jj < 4; ++jj) {
        int jl = jj * 16 + tx;
        int j = j0 + jl;
        float v = (j == gi) ? 0.f : acc[q][jj] * rq * rjs[jl];
        top3_ins(tv[q], ti[q], v, j);
      }
    }
    __syncthreads();
  }
#pragma unroll
  for (int q = 0; q < 2; ++q) {
    int r = ty * 2 + q;
#pragma unroll
    for (int s = 0; s < 3; ++s) { mv_s[r][tx][s] = tv[q][s]; mi_s[r][tx][s] = ti[q][s]; }
  }
  __syncthreads();
  if (t < GI) {
    float bv[3] = {-FLT_MAX, -FLT_MAX, -FLT_MAX};
    int bi[3] = {0x7fffffff, 0x7fffffff, 0x7fffffff};
    for (int u = 0; u < 16; ++u)
#pragma unroll
      for (int s = 0; s < 3; ++s) top3_ins(bv, bi, mv_s[t][u][s], mi_s[t][u][s]);
#pragma unroll
    for (int s = 0; s < 3; ++s) {
      gvals[(size_t)(i0 + t) * 3 + s] = bv[s];
      gidx[(size_t)(i0 + t) * 3 + s] = bi[s];
    }
  }
}

// ---------------- sparse scatter: hidden3 = hs2c^T @ h_shared ----------------
__global__ __launch_bounds__(128) void k_scatter(const float* __restrict__ hs,
      const float* __restrict__ gvals, const int* __restrict__ gidx,
      float* __restrict__ hidden3, float* __restrict__ colsum3) {
  int i = blockIdx.x, t = threadIdx.x;
  float xs = hs[(size_t)i * H_ + t];
#pragma unroll
  for (int k = 0; k < 3; ++k) {
    int j = gidx[i * 3 + k];
    float v = gvals[i * 3 + k];
    atomicAdd(&hidden3[(size_t)j * H_ + t], v * xs);
  }
  if (t == 0) {
#pragma unroll
    for (int k = 0; k < 3; ++k) atomicAdd(&colsum3[gidx[i * 3 + k]], gvals[i * 3 + k]);
  }
}

__global__ __launch_bounds__(128) void k_h3fin(float* __restrict__ hidden3,
      const float* __restrict__ hs, const float* __restrict__ colsum3,
      const float* __restrict__ diagv, float* __restrict__ rn3, int* __restrict__ keep2) {
  __shared__ float buf[128];
  int j = blockIdx.x, t = threadIdx.x;
  float v = hidden3[(size_t)j * H_ + t];
  if (colsum3[j] != 0.f) v += diagv[j] * hs[(size_t)j * H_ + t];
  hidden3[(size_t)j * H_ + t] = v;
  float ss = bred_sum128(v * v, buf);
  float sm = bred_sum128(v, buf);
  if (t == 0) {
    rn3[j] = (ss > 0.f) ? 1.f / sqrtf(ss) : 0.f;
    keep2[j] = (sm != 0.f) ? 1 : 0;
  }
}

// ---------------- attention prep: bf16 Qn/Kn, transposed V, keep as float ----------
__global__ __launch_bounds__(256) void k_prep_attn(const float* __restrict__ hs,
      const float* __restrict__ h3, const float* __restrict__ rqh,
      const float* __restrict__ rn3, const int* __restrict__ keep2,
      ushort* __restrict__ Qn, ushort* __restrict__ Kn, ushort* __restrict__ Vt,
      float* __restrict__ keepf) {
  __shared__ ushort T[H_][68];
  int t = threadIdx.x;
  int i0 = blockIdx.x * 64;
  int r = i0 + (t >> 2);
  int c0 = (t & 3) * 32;
  float rq = rqh[r], r3 = rn3[r];
  for (int c = c0; c < c0 + 32; c += 4) {
    float4 hv = *(const float4*)&hs[(size_t)r * H_ + c];
    float4 h3v = *(const float4*)&h3[(size_t)r * H_ + c];
    ushort q4[4] = {f2bf(hv.x * rq), f2bf(hv.y * rq), f2bf(hv.z * rq), f2bf(hv.w * rq)};
    ushort k4[4] = {f2bf(h3v.x * r3), f2bf(h3v.y * r3), f2bf(h3v.z * r3), f2bf(h3v.w * r3)};
    *(ushort4*)&Qn[(size_t)r * H_ + c] = *(ushort4*)q4;
    *(ushort4*)&Kn[(size_t)r * H_ + c] = *(ushort4*)k4;
    T[c + 0][r - i0] = f2bf(h3v.x);
    T[c + 1][r - i0] = f2bf(h3v.y);
    T[c + 2][r - i0] = f2bf(h3v.z);
    T[c + 3][r - i0] = f2bf(h3v.w);
  }
  if (t < 64) keepf[i0 + t] = (float)keep2[i0 + t];
  __syncthreads();
  int h = t >> 1, off = (t & 1) * 32;
  for (int u = 0; u < 32; u += 4) {
    ushort4 vv;
    vv.x = T[h][off + u]; vv.y = T[h][off + u + 1];
    vv.z = T[h][off + u + 2]; vv.w = T[h][off + u + 3];
    *(ushort4*)&Vt[(size_t)h * N_ + i0 + off + u] = vv;
  }
}

// ---------------- MFMA flash attention (j-split partials) ----------------
// 1 wave/block, 32 q-rows (2 m-tiles), j-tile 64, grid (N/32, JSPLIT).
#define JSPLIT 8
__global__ __launch_bounds__(64) void k_attn_mfma(const ushort* __restrict__ Qn,
      const ushort* __restrict__ Kn, const ushort* __restrict__ Vt,
      const float* __restrict__ keepf, float* __restrict__ Opart,
      float* __restrict__ Mpart, float* __restrict__ Lpart) {
  __shared__ ushort Ps[32][72];  // stride 72 shorts = 144 B: 16B-aligned rows, low-conflict
  int l = threadIdx.x;
  int lo16 = l & 15, hi = l >> 4;     // hi in 0..3
  int i0 = blockIdx.x * 32;
  int sp = blockIdx.y;
  const int jspan = N_ / JSPLIT;      // 1024

  bfrag aq[2][4];
#pragma unroll
  for (int mt = 0; mt < 2; ++mt)
#pragma unroll
    for (int kc = 0; kc < 4; ++kc)
      aq[mt][kc] = *(const bfrag*)&Qn[(size_t)(i0 + mt * 16 + lo16) * H_ + kc * 32 + hi * 8];

  f4 O[2][8];
#pragma unroll
  for (int mt = 0; mt < 2; ++mt)
#pragma unroll
    for (int ns = 0; ns < 8; ++ns) O[mt][ns] = (f4){0.f, 0.f, 0.f, 0.f};
  f4 m4[2], l4[2];
#pragma unroll
  for (int mt = 0; mt < 2; ++mt) {
    m4[mt] = (f4){-FLT_MAX, -FLT_MAX, -FLT_MAX, -FLT_MAX};
    l4[mt] = (f4){0.f, 0.f, 0.f, 0.f};
  }

  for (int jt = 0; jt < jspan / 64; ++jt) {
    int j0 = sp * jspan + jt * 64;
    float kp[4];
#pragma unroll
    for (int js = 0; js < 4; ++js) kp[js] = keepf[j0 + js * 16 + lo16];

#pragma unroll
    for (int mt = 0; mt < 2; ++mt) {
      f4 S[4];
#pragma unroll
      for (int js = 0; js < 4; ++js) {
        f4 acc = (f4){0.f, 0.f, 0.f, 0.f};
#pragma unroll
        for (int kc = 0; kc < 4; ++kc) {
          bfrag b = *(const bfrag*)&Kn[(size_t)(j0 + js * 16 + lo16) * H_ + kc * 32 + hi * 8];
          acc = __builtin_amdgcn_mfma_f32_16x16x32_bf16(aq[mt][kc], b, acc, 0, 0, 0);
        }
        S[js] = acc;
      }
      // masked copy for max/exp (NaN-free: -FLT_MAX sentinels, no infinities)
      f4 Sm[4];
#pragma unroll
      for (int js = 0; js < 4; ++js)
#pragma unroll
        for (int r = 0; r < 4; ++r)
          Sm[js][r] = (kp[js] > 0.f) ? S[js][r] : -FLT_MAX;
      f4 tm;
#pragma unroll
      for (int r = 0; r < 4; ++r)
        tm[r] = fmaxf(fmaxf(Sm[0][r], Sm[1][r]), fmaxf(Sm[2][r], Sm[3][r]));
#pragma unroll
      for (int x = 1; x <= 8; x <<= 1)
#pragma unroll
        for (int r = 0; r < 4; ++r) tm[r] = fmaxf(tm[r], __shfl_xor(tm[r], x, 16));
      f4 nm, alpha;
#pragma unroll
      for (int r = 0; r < 4; ++r) {
        nm[r] = fmaxf(m4[mt][r], tm[r]);
        alpha[r] = expf(m4[mt][r] - nm[r]);  // both -FLT_MAX -> exp(0)=1, harmless (O=l=0)
      }
      m4[mt] = nm;
      f4 ps = (f4){0.f, 0.f, 0.f, 0.f};
#pragma unroll
      for (int js = 0; js < 4; ++js)
#pragma unroll
        for (int r = 0; r < 4; ++r) {
          float p = kp[js] * expf(Sm[js][r] - nm[r]);
          ps[r] += p;
          Ps[mt * 16 + hi * 4 + r][js * 16 + lo16] = f2bf(p);
        }
#pragma unroll
      for (int x = 1; x <= 8; x <<= 1)
#pragma unroll
        for (int r = 0; r < 4; ++r) ps[r] += __shfl_xor(ps[r], x, 16);
#pragma unroll
      for (int r = 0; r < 4; ++r) l4[mt][r] = l4[mt][r] * alpha[r] + ps[r];
#pragma unroll
      for (int ns = 0; ns < 8; ++ns)
#pragma unroll
        for (int r = 0; r < 4; ++r) O[mt][ns][r] *= alpha[r];
    }
    __syncthreads();
#pragma unroll
    for (int kc = 0; kc < 2; ++kc) {
      bfrag ap0 = *(const bfrag*)&Ps[lo16][kc * 32 + hi * 8];
      bfrag ap1 = *(const bfrag*)&Ps[16 + lo16][kc * 32 + hi * 8];
#pragma unroll
      for (int ns = 0; ns < 8; ++ns) {
        bfrag bv = *(const bfrag*)&Vt[(size_t)(ns * 16 + lo16) * N_ + j0 + kc * 32 + hi * 8];
        O[0][ns] = __builtin_amdgcn_mfma_f32_16x16x32_bf16(ap0, bv, O[0][ns], 0, 0, 0);
        O[1][ns] = __builtin_amdgcn_mfma_f32_16x16x32_bf16(ap1, bv, O[1][ns], 0, 0, 0);
      }
    }
    __syncthreads();
  }
  // write partials (unnormalized O + per-row m,l)
#pragma unroll
  for (int mt = 0; mt < 2; ++mt)
#pragma unroll
    for (int ns = 0; ns < 8; ++ns)
#pragma unroll
      for (int r = 0; r < 4; ++r) {
        int row = i0 + mt * 16 + hi * 4 + r;
        Opart[((size_t)sp * N_ + row) * H_ + ns * 16 + lo16] = O[mt][ns][r];
      }
  if (lo16 == 0) {
#pragma unroll
    for (int mt = 0; mt < 2; ++mt)
#pragma unroll
      for (int r = 0; r < 4; ++r) {
        size_t idx = (size_t)sp * N_ + i0 + mt * 16 + hi * 4 + r;
        Mpart[idx] = m4[mt][r];
        Lpart[idx] = l4[mt][r];
      }
  }
}

__global__ __launch_bounds__(128) void k_attn_merge(const float* __restrict__ Opart,
      const float* __restrict__ Mpart, const float* __restrict__ Lpart,
      float* __restrict__ outp) {
  int i = blockIdx.x, t = threadIdx.x;
  float mg = -FLT_MAX;
#pragma unroll
  for (int s = 0; s < JSPLIT; ++s) mg = fmaxf(mg, Mpart[(size_t)s * N_ + i]);
  float w[JSPLIT];
  float lg = 0.f;
#pragma unroll
  for (int s = 0; s < JSPLIT; ++s) {
    float ms = Mpart[(size_t)s * N_ + i];
    float ws = (mg > -0.5f * FLT_MAX) ? expf(ms - mg) : 0.f;
    w[s] = ws;
    lg += ws * Lpart[(size_t)s * N_ + i];
  }
  float inv = (lg > 0.f) ? 1.f / lg : 0.f;
  float acc = 0.f;
#pragma unroll
  for (int s = 0; s < JSPLIT; ++s)
    acc += w[s] * Opart[((size_t)s * N_ + i) * H_ + t];
  outp[(size_t)i * H_ + t] = acc * inv;
}

// ---------------- elementwise ----------------
__global__ __launch_bounds__(256) void k_sub2(const float4* __restrict__ a,
      const float4* __restrict__ b, float4* __restrict__ o) {
  int i = blockIdx.x * 256 + threadIdx.x;
  float4 x = a[i], y = b[i], r;
  r.x = x.x - y.x; r.y = x.y - y.y; r.z = x.z - y.z; r.w = x.w - y.w;
  o[i] = r;
}

__global__ __launch_bounds__(256) void k_sub3(const float4* __restrict__ a,
      const float4* __restrict__ b, const float4* __restrict__ c, float4* __restrict__ o) {
  int i = blockIdx.x * 256 + threadIdx.x;
  float4 x = a[i], y = b[i], z = c[i], r;
  r.x = x.x - y.x - z.x; r.y = x.y - y.y - z.y; r.z = x.z - y.z - z.z; r.w = x.w - y.w - z.w;
  o[i] = r;
}

__global__ __launch_bounds__(128) void k_pred(const float* __restrict__ a,
      const float* __restrict__ b, const float* __restrict__ c,
      const float* __restrict__ wout, const float* __restrict__ bout,
      float* __restrict__ outp) {
  __shared__ float buf[128];
  int i = blockIdx.x, t = threadIdx.x;
  size_t idx = (size_t)i * H_ + t;
  float v = (a[idx] + b[idx] + c[idx]) * wout[t];
  float s = bred_sum128(v, buf);
  if (t == 0) outp[i] = s + bout[0];
}

// ---------------- host ----------------
extern "C" void kernel_launch(void* const* d_in, const int* in_sizes, int n_in,
                              void* d_out, int out_size, void* d_ws, size_t ws_size,
                              hipStream_t stream) {
  const float* x          = (const float*)d_in[0];
  const float* mv         = (const float*)d_in[1];
  const int*   cm         = (const int*)d_in[2];
  const float* W_ps       = (const float*)d_in[3];
  const float* b_ps       = (const float*)d_in[4];
  const float* W_hs       = (const float*)d_in[5];
  const float* b_hs       = (const float*)d_in[6];
  const float* W_ps_fore  = (const float*)d_in[7];
  const float* b_ps_fore  = (const float*)d_in[8];
  const float* W_hs_fore  = (const float*)d_in[9];
  const float* b_hs_fore  = (const float*)d_in[10];
  const float* W_ps_back  = (const float*)d_in[11];
  const float* b_ps_back  = (const float*)d_in[12];
  const float* W_hs_back  = (const float*)d_in[13];
  const float* b_hs_back  = (const float*)d_in[14];
  const float* W_indi     = (const float*)d_in[15];
  const float* b_indi     = (const float*)d_in[16];
  const float* W_out      = (const float*)d_in[23];
  const float* b_out      = (const float*)d_in[24];
  float* outp = (float*)d_out;

  float* W = (float*)d_ws;
  const size_t NC = (size_t)N_ * C_;   // NOTE: NC = 4*NH (C/H = 4), Sbuf holds exactly 4 NH-slices
  const size_t NH = (size_t)N_ * H_;
  const size_t CH = (size_t)C_ * H_;
  float* Sbuf = W;
  // Sbuf (NC = 4*NH floats) is free after stage-3's T1 GEMM; reuse its 4 NH-slices:
  float* pback   = Sbuf;
  float* outps   = Sbuf + NH;
  float* hback   = Sbuf + 2 * NH;
  float* outindi = Sbuf + 3 * NH;
  size_t off = NC;
  float* T1       = W + off; off += NH;   // attention output / scratch
  float* p_shared = W + off; off += NH;
  float* h_shared = W + off; off += NH;   // later reused for indiv
  float* hidden3  = W + off; off += NH;
  float* h_info   = W + off; off += NH;
  float* out_hs   = W + off; off += NH;
  float* hidden1  = W + off; off += CH;
  float* hidden2  = W + off; off += CH;
  float* colsum1   = W + off; off += C_;
  float* colmax    = W + off; off += C_;
  float* colsumexp = W + off; off += C_;
  float* rny2      = W + off; off += C_;
  float* partb     = W + off; off += 32 * C_;
  float* rnx     = W + off; off += N_;
  float* rqh     = W + off; off += N_;
  float* diagv   = W + off; off += N_;
  float* colsum3 = W + off; off += N_;
  float* rn3     = W + off; off += N_;
  float* gvals   = W + off; off += 3 * N_;
  float* Mpart   = W + off; off += (size_t)JSPLIT * N_;
  float* Lpart   = W + off; off += (size_t)JSPLIT * N_;
  float* keepf   = W + off; off += N_;
  int* keep1 = (int*)(W + off); off += C_;
  int* keep2 = (int*)(W + off); off += N_;
  int* gidx  = (int*)(W + off); off += 3 * N_;
  ushort* Qn = (ushort*)(W + off); off += NH / 2;   // NH bf16 = NH/2 floats
  ushort* Kn = (ushort*)(W + off); off += NH / 2;
  ushort* Vt = (ushort*)(W + off); off += NH / 2;
  float* Opart = W + off; off += (size_t)JSPLIT * NH;   // 33.5 MB, tail-allocated (no overlap!)

  hipMemsetAsync(colsum1, 0, C_ * sizeof(float), stream);
  hipMemsetAsync(hidden1, 0, CH * sizeof(float), stream);
  hipMemsetAsync(hidden2, 0, CH * sizeof(float), stream);
  hipMemsetAsync(hidden3, 0, NH * sizeof(float), stream);
  hipMemsetAsync(colsum3, 0, N_ * sizeof(float), stream);

  // stage 1: market-value aggregation
  k_colsum1<<<dim3(2, 32), 256, 0, stream>>>(cm, mv, colsum1);
  k_agg<0><<<dim3(16, 8), 256, 0, stream>>>(x, cm, mv, nullptr, nullptr, hidden1);
  k_fin_hidden1<<<C_, 128, 0, stream>>>(hidden1, colsum1, keep1);
  k_rowstats<<<N_, 128, 0, stream>>>(x, rnx, nullptr, nullptr);

  // stage 2: softmax over stocks, hidden2
  k_gemm<1, 0><<<dim3(C_ / 64, N_ / 64), 256, 0, stream>>>(
      x, H_, hidden1, H_, Sbuf, C_, N_, C_, H_, nullptr, nullptr, nullptr);
  k_colmax_part<<<32, 256, 0, stream>>>(Sbuf, partb);
  k_colfin_max<<<1, 512, 0, stream>>>(partb, colmax);
  k_colsum_part<<<32, 256, 0, stream>>>(Sbuf, colmax, partb);
  k_colfin_sum<<<1, 512, 0, stream>>>(partb, colsumexp);
  k_agg<1><<<dim3(16, 8), 256, 0, stream>>>(x, nullptr, nullptr, Sbuf, colmax, hidden2);
  k_fin_hidden2<<<C_, 128, 0, stream>>>(hidden2, colsumexp, rny2);

  // stage 3: c2s softmax + p branch
  k_gemm<1, 0><<<dim3(C_ / 64, N_ / 64), 256, 0, stream>>>(
      x, H_, hidden2, H_, Sbuf, C_, N_, C_, H_, nullptr, rnx, rny2);
  k_rowsoftmax<<<N_, 256, 0, stream>>>(Sbuf, keep1);
  k_gemm<0, 0><<<dim3(H_ / 64, N_ / 64), 256, 0, stream>>>(
      Sbuf, C_, hidden2, H_, T1, H_, N_, H_, C_, nullptr, nullptr, nullptr);
  k_gemm<0, 0><<<dim3(2, 128), 256, 0, stream>>>(
      T1, H_, W_ps, H_, p_shared, H_, N_, H_, H_, b_ps, nullptr, nullptr);
  k_gemm<0, 0><<<dim3(2, 128), 256, 0, stream>>>(
      p_shared, H_, W_ps_back, H_, pback, H_, N_, H_, H_, b_ps_back, nullptr, nullptr);
  k_gemm<0, 1><<<dim3(2, 128), 256, 0, stream>>>(
      p_shared, H_, W_ps_fore, H_, outps, H_, N_, H_, H_, b_ps_fore, nullptr, nullptr);

  // stage 4: h_shared, N x N top-3 graph (fp32), sparse aggregation
  k_sub2<<<NH / 4 / 256, 256, 0, stream>>>((const float4*)x, (const float4*)pback,
                                           (float4*)h_shared);
  k_rowstats<<<N_, 128, 0, stream>>>(h_shared, rqh, diagv, nullptr);
  k_gram_top3<<<N_ / GI, 256, 0, stream>>>(h_shared, rqh, gvals, gidx);
  k_scatter<<<N_, 128, 0, stream>>>(h_shared, gvals, gidx, hidden3, colsum3);
  k_h3fin<<<N_, 128, 0, stream>>>(hidden3, h_shared, colsum3, diagv, rn3, keep2);

  // stage 5: MFMA flash attention, h branch
  k_prep_attn<<<N_ / 64, 256, 0, stream>>>(h_shared, hidden3, rqh, rn3, keep2,
                                           Qn, Kn, Vt, keepf);
  k_attn_mfma<<<dim3(N_ / 32, JSPLIT), 64, 0, stream>>>(Qn, Kn, Vt, keepf,
                                                        Opart, Mpart, Lpart);
  k_attn_merge<<<N_, 128, 0, stream>>>(Opart, Mpart, Lpart, T1);
  k_gemm<0, 0><<<dim3(2, 128), 256, 0, stream>>>(
      T1, H_, W_hs, H_, h_info, H_, N_, H_, H_, b_hs, nullptr, nullptr);
  k_gemm<0, 0><<<dim3(2, 128), 256, 0, stream>>>(
      h_info, H_, W_hs_back, H_, hback, H_, N_, H_, H_, b_hs_back, nullptr, nullptr);
  k_gemm<0, 1><<<dim3(2, 128), 256, 0, stream>>>(
      h_info, H_, W_hs_fore, H_, out_hs, H_, N_, H_, H_, b_hs_fore, nullptr, nullptr);

  // stage 6: individual branch + final projection
  k_sub3<<<NH / 4 / 256, 256, 0, stream>>>((const float4*)x, (const float4*)pback,
                                           (const float4*)hback, (float4*)h_shared);
  k_gemm<0, 1><<<dim3(2, 128), 256, 0, stream>>>(
      h_shared, H_, W_indi, H_, outindi, H_, N_, H_, H_, b_indi, nullptr, nullptr);
  k_pred<<<N_, 128, 0, stream>>>(outps, out_hs, outindi, W_out, b_out, outp);
}

// Round 4
// 1226.002 us; speedup vs baseline: 2.2175x; 1.4897x over previous
//
#include <hip/hip_runtime.h>
#include <float.h>
#include <math.h>

#define N_ 8192
#define C_ 512
#define H_ 128

typedef __attribute__((ext_vector_type(8))) short bfrag;
typedef __attribute__((ext_vector_type(4))) float f4;

__device__ __forceinline__ ushort f2bf(float f) {
  unsigned u = __float_as_uint(f);
  unsigned r = (u + 0x7fffu + ((u >> 16) & 1u)) >> 16;
  return (ushort)r;
}

// ---------------- helpers ----------------
__device__ __forceinline__ float bred_sum128(float v, float* buf) {
  int t = threadIdx.x;
  buf[t] = v; __syncthreads();
  for (int s = 64; s > 0; s >>= 1) {
    if (t < s) buf[t] += buf[t + s];
    __syncthreads();
  }
  float r = buf[0]; __syncthreads();
  return r;
}

__device__ __forceinline__ void top3_ins(float (&tv)[3], int (&ti)[3], float v, int j) {
  bool b2 = (v > tv[2]) || (v == tv[2] && j < ti[2]);
  if (!b2) return;
  bool b1 = (v > tv[1]) || (v == tv[1] && j < ti[1]);
  if (b1) {
    tv[2] = tv[1]; ti[2] = ti[1];
    bool b0 = (v > tv[0]) || (v == tv[0] && j < ti[0]);
    if (b0) { tv[1] = tv[0]; ti[1] = ti[0]; tv[0] = v; ti[0] = j; }
    else    { tv[1] = v;     ti[1] = j; }
  } else { tv[2] = v; ti[2] = j; }
}

// ---------------- stage 1: concept aggregation ----------------
__global__ __launch_bounds__(256) void k_colsum1(const int* __restrict__ cm,
      const float* __restrict__ mv, float* __restrict__ colsum1) {
  int t = threadIdx.x;
  int c = blockIdx.x * 256 + t;
  int r0 = blockIdx.y * 256;
  float acc = 0.f;
  for (int r = 0; r < 256; ++r) {
    int i = r0 + r;
    acc += (float)cm[(size_t)i * C_ + c] * mv[i];
  }
  atomicAdd(&colsum1[c], acc);
}

template<int MODE>
__global__ __launch_bounds__(256) void k_agg(const float* __restrict__ x,
      const int* __restrict__ cm, const float* __restrict__ mv,
      const float* __restrict__ S, const float* __restrict__ colmax,
      float* __restrict__ outCH) {
  __shared__ float ws[8][32];
  int t = threadIdx.x;
  int cbase = blockIdx.x * 32;
  int h = t & 127, half = t >> 7;
  float acc[16];
#pragma unroll
  for (int k = 0; k < 16; ++k) acc[k] = 0.f;
  int sr = t >> 5, sc = t & 31;
  for (int sub = 0; sub < 128; ++sub) {
    int ibase = blockIdx.y * 1024 + sub * 8;
    {
      int i = ibase + sr, c = cbase + sc;
      float w;
      if (MODE == 0) w = cm[(size_t)i * C_ + c] ? mv[i] : 0.f;
      else           w = expf(S[(size_t)i * C_ + c] - colmax[c]);
      ws[sr][sc] = w;
    }
    __syncthreads();
#pragma unroll
    for (int r = 0; r < 8; ++r) {
      float xv = x[(size_t)(ibase + r) * H_ + h];
      const float* wr = &ws[r][half * 16];
#pragma unroll
      for (int k = 0; k < 16; ++k) acc[k] += wr[k] * xv;
    }
    __syncthreads();
  }
#pragma unroll
  for (int k = 0; k < 16; ++k)
    atomicAdd(&outCH[(size_t)(cbase + half * 16 + k) * H_ + h], acc[k]);
}

__global__ __launch_bounds__(128) void k_fin_hidden1(float* __restrict__ h1,
      const float* __restrict__ colsum1, int* __restrict__ keep1) {
  __shared__ float buf[128];
  int c = blockIdx.x, t = threadIdx.x;
  float v = h1[(size_t)c * H_ + t] / (colsum1[c] + 1.f);
  h1[(size_t)c * H_ + t] = v;
  float sm = bred_sum128(v, buf);
  if (t == 0) keep1[c] = (sm != 0.f) ? 1 : 0;
}

__global__ __launch_bounds__(128) void k_fin_hidden2(float* __restrict__ h2,
      const float* __restrict__ colsumexp, float* __restrict__ rny) {
  __shared__ float buf[128];
  int c = blockIdx.x, t = threadIdx.x;
  float v = h2[(size_t)c * H_ + t] / colsumexp[c];
  h2[(size_t)c * H_ + t] = v;
  float ss = bred_sum128(v * v, buf);
  if (t == 0) rny[c] = (ss > 0.f) ? 1.f / sqrtf(ss) : 0.f;
}

__global__ __launch_bounds__(128) void k_rowstats(const float* __restrict__ A,
      float* __restrict__ rinv, float* __restrict__ diag, int* __restrict__ keep) {
  __shared__ float buf[128];
  int i = blockIdx.x, t = threadIdx.x;
  float v = A[(size_t)i * H_ + t];
  float ss = bred_sum128(v * v, buf);
  float sm = bred_sum128(v, buf);
  if (t == 0) {
    float nr = sqrtf(ss);
    if (rinv) rinv[i] = (ss > 0.f) ? 1.f / nr : 0.f;
    if (diag) diag[i] = (ss > 0.f) ? ss / (nr * nr) : 0.f;
    if (keep) keep[i] = (sm != 0.f) ? 1 : 0;
  }
}

// ---------------- generic fp32 tiled GEMM ----------------
template<int TRANSB, int ACT>
__global__ __launch_bounds__(256) void k_gemm(const float* __restrict__ A, int lda,
      const float* __restrict__ B, int ldb, float* __restrict__ Cc, int ldc,
      int M, int Nn, int Kk, const float* __restrict__ bias,
      const float* __restrict__ rowscale, const float* __restrict__ colscale) {
  __shared__ float As[16][68];
  __shared__ float Bs[16][68];
  int t = threadIdx.x;
  int n0 = blockIdx.x * 64, m0 = blockIdx.y * 64;
  int ty = t >> 4, tx = t & 15;
  float acc[4][4] = {};
  for (int k0 = 0; k0 < Kk; k0 += 16) {
#pragma unroll
    for (int li = t; li < 1024; li += 256) {
      int r = li >> 4, c = li & 15;
      As[c][r] = A[(size_t)(m0 + r) * lda + k0 + c];
    }
    if (TRANSB) {
#pragma unroll
      for (int li = t; li < 1024; li += 256) {
        int r = li >> 4, c = li & 15;
        Bs[c][r] = B[(size_t)(n0 + r) * ldb + k0 + c];
      }
    } else {
#pragma unroll
      for (int li = t; li < 1024; li += 256) {
        int nn = li & 63, c = li >> 6;
        Bs[c][nn] = B[(size_t)(k0 + c) * ldb + n0 + nn];
      }
    }
    __syncthreads();
#pragma unroll
    for (int kk = 0; kk < 16; ++kk) {
      float4 av = *(const float4*)&As[kk][ty * 4];
      float4 bv = *(const float4*)&Bs[kk][tx * 4];
      float a0 = av.x, a1 = av.y, a2 = av.z, a3 = av.w;
      float b0 = bv.x, b1 = bv.y, b2 = bv.z, b3 = bv.w;
      acc[0][0] += a0 * b0; acc[0][1] += a0 * b1; acc[0][2] += a0 * b2; acc[0][3] += a0 * b3;
      acc[1][0] += a1 * b0; acc[1][1] += a1 * b1; acc[1][2] += a1 * b2; acc[1][3] += a1 * b3;
      acc[2][0] += a2 * b0; acc[2][1] += a2 * b1; acc[2][2] += a2 * b2; acc[2][3] += a2 * b3;
      acc[3][0] += a3 * b0; acc[3][1] += a3 * b1; acc[3][2] += a3 * b2; acc[3][3] += a3 * b3;
    }
    __syncthreads();
  }
#pragma unroll
  for (int ii = 0; ii < 4; ++ii) {
    int row = m0 + ty * 4 + ii;
    float rs = rowscale ? rowscale[row] : 1.f;
#pragma unroll
    for (int jj = 0; jj < 4; ++jj) {
      int col = n0 + tx * 4 + jj;
      float v = acc[ii][jj] * rs;
      if (colscale) v *= colscale[col];
      if (bias) v += bias[col];
      if (ACT) v = (v > 0.f) ? v : 0.01f * v;
      Cc[(size_t)row * ldc + col] = v;
    }
  }
}

// ---------------- column softmax over S[N,C] ----------------
__global__ __launch_bounds__(256) void k_colmax_part(const float* __restrict__ S,
      float* __restrict__ part) {
  int t = threadIdx.x, b = blockIdx.x;
  int r0 = b * 256;
  float m0 = -FLT_MAX, m1 = -FLT_MAX;
  for (int r = 0; r < 256; ++r) {
    const float* row = S + (size_t)(r0 + r) * C_;
    m0 = fmaxf(m0, row[t]);
    m1 = fmaxf(m1, row[t + 256]);
  }
  part[(size_t)b * C_ + t] = m0;
  part[(size_t)b * C_ + t + 256] = m1;
}

__global__ __launch_bounds__(256) void k_colsum_part(const float* __restrict__ S,
      const float* __restrict__ colmax, float* __restrict__ part) {
  int t = threadIdx.x, b = blockIdx.x;
  int r0 = b * 256;
  float cm0 = colmax[t], cm1 = colmax[t + 256];
  float s0 = 0.f, s1 = 0.f;
  for (int r = 0; r < 256; ++r) {
    const float* row = S + (size_t)(r0 + r) * C_;
    s0 += expf(row[t] - cm0);
    s1 += expf(row[t + 256] - cm1);
  }
  part[(size_t)b * C_ + t] = s0;
  part[(size_t)b * C_ + t + 256] = s1;
}

__global__ __launch_bounds__(512) void k_colfin_max(const float* __restrict__ part,
      float* __restrict__ outv) {
  int c = threadIdx.x;
  float m = -FLT_MAX;
  for (int b = 0; b < 32; ++b) m = fmaxf(m, part[(size_t)b * C_ + c]);
  outv[c] = m;
}

__global__ __launch_bounds__(512) void k_colfin_sum(const float* __restrict__ part,
      float* __restrict__ outv) {
  int c = threadIdx.x;
  float s = 0.f;
  for (int b = 0; b < 32; ++b) s += part[(size_t)b * C_ + c];
  outv[c] = s;
}

// ---------------- row softmax (512 cols) with keep mask ----------------
__global__ __launch_bounds__(256) void k_rowsoftmax(float* __restrict__ Sm,
      const int* __restrict__ keep1) {
  __shared__ float buf[256];
  int i = blockIdx.x, t = threadIdx.x;
  float* row = Sm + (size_t)i * C_;
  int k0 = keep1[t], k1 = keep1[t + 256];
  float v0 = k0 ? row[t] : -FLT_MAX;
  float v1 = k1 ? row[t + 256] : -FLT_MAX;
  buf[t] = fmaxf(v0, v1); __syncthreads();
  for (int s = 128; s > 0; s >>= 1) {
    if (t < s) buf[t] = fmaxf(buf[t], buf[t + s]);
    __syncthreads();
  }
  float m = buf[0]; __syncthreads();
  float e0 = k0 ? expf(v0 - m) : 0.f;
  float e1 = k1 ? expf(v1 - m) : 0.f;
  buf[t] = e0 + e1; __syncthreads();
  for (int s = 128; s > 0; s >>= 1) {
    if (t < s) buf[t] += buf[t + s];
    __syncthreads();
  }
  float inv = 1.f / buf[0];
  row[t] = e0 * inv;
  row[t + 256] = e1 * inv;
}

// ---------------- gram prep: normalized rows split into bf16 hi + lo ----------------
__global__ __launch_bounds__(256) void k_prep_gram(const float* __restrict__ hs,
      const float* __restrict__ rn, ushort* __restrict__ Ghi, ushort* __restrict__ Glo) {
  int t = threadIdx.x;
  int row = blockIdx.x * 8 + (t >> 5);
  int c = (t & 31) * 4;
  float r = rn[row];
  float4 v = *(const float4*)&hs[(size_t)row * H_ + c];
  float q[4] = {v.x * r, v.y * r, v.z * r, v.w * r};
  ushort hi[4], lo[4];
#pragma unroll
  for (int k = 0; k < 4; ++k) {
    hi[k] = f2bf(q[k]);
    float hf = __uint_as_float(((unsigned)hi[k]) << 16);
    lo[k] = f2bf(q[k] - hf);
  }
  *(ushort4*)&Ghi[(size_t)row * H_ + c] = *(ushort4*)hi;
  *(ushort4*)&Glo[(size_t)row * H_ + c] = *(ushort4*)lo;
}

// ---------------- N x N Gram via compensated-bf16 MFMA + fused top-3 candidates ------
// 1 wave/block, 32 q-rows (2 m-tiles), grid (N/32, GSPLIT). Scores = hi*hi + hi*lo + lo*hi
// (error ~1e-5); emits per-split top-3 candidate INDICES only (rescored exactly later).
#define GSPLIT 8
__global__ __launch_bounds__(64) void k_gram_mfma(const ushort* __restrict__ Ghi,
      const ushort* __restrict__ Glo, int* __restrict__ Gip) {
  __shared__ float sv[64][24];
  __shared__ int   si[64][24];
  int l = threadIdx.x;
  int lo16 = l & 15, quad = l >> 4;
  int i0 = blockIdx.x * 32;
  int sp = blockIdx.y;
  const int jspan = N_ / GSPLIT;   // 1024

  bfrag ahi[2][4], alo[2][4];
#pragma unroll
  for (int mt = 0; mt < 2; ++mt)
#pragma unroll
    for (int kc = 0; kc < 4; ++kc) {
      size_t base = (size_t)(i0 + mt * 16 + lo16) * H_ + kc * 32 + quad * 8;
      ahi[mt][kc] = *(const bfrag*)&Ghi[base];
      alo[mt][kc] = *(const bfrag*)&Glo[base];
    }

  float tv[2][4][3]; int ti[2][4][3];
#pragma unroll
  for (int mt = 0; mt < 2; ++mt)
#pragma unroll
    for (int r = 0; r < 4; ++r)
#pragma unroll
      for (int s = 0; s < 3; ++s) { tv[mt][r][s] = -FLT_MAX; ti[mt][r][s] = 0x7fffffff; }

  for (int jt = 0; jt < jspan / 64; ++jt) {
    int j0 = sp * jspan + jt * 64;
#pragma unroll
    for (int js = 0; js < 4; ++js) {
      int j = j0 + js * 16 + lo16;
      bfrag bhi[4], blo[4];
#pragma unroll
      for (int kc = 0; kc < 4; ++kc) {
        size_t base = (size_t)j * H_ + kc * 32 + quad * 8;
        bhi[kc] = *(const bfrag*)&Ghi[base];
        blo[kc] = *(const bfrag*)&Glo[base];
      }
#pragma unroll
      for (int mt = 0; mt < 2; ++mt) {
        f4 acc = (f4){0.f, 0.f, 0.f, 0.f};
#pragma unroll
        for (int kc = 0; kc < 4; ++kc)
          acc = __builtin_amdgcn_mfma_f32_16x16x32_bf16(ahi[mt][kc], bhi[kc], acc, 0, 0, 0);
#pragma unroll
        for (int kc = 0; kc < 4; ++kc)
          acc = __builtin_amdgcn_mfma_f32_16x16x32_bf16(ahi[mt][kc], blo[kc], acc, 0, 0, 0);
#pragma unroll
        for (int kc = 0; kc < 4; ++kc)
          acc = __builtin_amdgcn_mfma_f32_16x16x32_bf16(alo[mt][kc], bhi[kc], acc, 0, 0, 0);
#pragma unroll
        for (int r = 0; r < 4; ++r) {
          int gi = i0 + mt * 16 + quad * 4 + r;
          float v = (j == gi) ? 0.f : acc[r];
          top3_ins(tv[mt][r], ti[mt][r], v, j);
        }
      }
    }
  }
#pragma unroll
  for (int mt = 0; mt < 2; ++mt)
#pragma unroll
    for (int r = 0; r < 4; ++r)
#pragma unroll
      for (int s = 0; s < 3; ++s) {
        sv[l][mt * 12 + r * 3 + s] = tv[mt][r][s];
        si[l][mt * 12 + r * 3 + s] = ti[mt][r][s];
      }
  __syncthreads();
  if (l < 32) {
    int mt = l >> 4, q2 = (l >> 2) & 3, r = l & 3;
    float bv[3] = {-FLT_MAX, -FLT_MAX, -FLT_MAX};
    int bi[3] = {0x7fffffff, 0x7fffffff, 0x7fffffff};
    for (int u = 0; u < 16; ++u) {
      int src = q2 * 16 + u;
#pragma unroll
      for (int s = 0; s < 3; ++s)
        top3_ins(bv, bi, sv[src][mt * 12 + r * 3 + s], si[src][mt * 12 + r * 3 + s]);
    }
    int grow = i0 + l;
#pragma unroll
    for (int s = 0; s < 3; ++s)
      Gip[((size_t)sp * N_ + grow) * 3 + s] = bi[s];
  }
}

// ---------------- exact fp32 rescore of 24 candidates/row -> final top-3 -------------
__global__ __launch_bounds__(256) void k_gram_rescore(const float* __restrict__ hs,
      const float* __restrict__ rn, const int* __restrict__ Gip,
      float* __restrict__ gvals, int* __restrict__ gidx) {
  int row = blockIdx.x * 4 + (threadIdx.x >> 6);
  int lane = threadIdx.x & 63;
  const float* qr = &hs[(size_t)row * H_];
  float q0 = qr[lane], q1 = qr[lane + 64];
  float rni = rn[row];
  float bv[3] = {-FLT_MAX, -FLT_MAX, -FLT_MAX};
  int bi[3] = {0x7fffffff, 0x7fffffff, 0x7fffffff};
  for (int s = 0; s < GSPLIT; ++s)
#pragma unroll
    for (int k = 0; k < 3; ++k) {
      int j = Gip[((size_t)s * N_ + row) * 3 + k];
      const float* jr = &hs[(size_t)j * H_];
      float d = q0 * jr[lane] + q1 * jr[lane + 64];
#pragma unroll
      for (int x = 1; x < 64; x <<= 1) d += __shfl_xor(d, x, 64);
      float v = (j == row) ? 0.f : d * rni * rn[j];
      top3_ins(bv, bi, v, j);
    }
  if (lane == 0) {
#pragma unroll
    for (int s = 0; s < 3; ++s) {
      gvals[(size_t)row * 3 + s] = bv[s];
      gidx[(size_t)row * 3 + s] = bi[s];
    }
  }
}

// ---------------- sparse scatter: hidden3 = hs2c^T @ h_shared ----------------
__global__ __launch_bounds__(128) void k_scatter(const float* __restrict__ hs,
      const float* __restrict__ gvals, const int* __restrict__ gidx,
      float* __restrict__ hidden3, float* __restrict__ colsum3) {
  int i = blockIdx.x, t = threadIdx.x;
  float xs = hs[(size_t)i * H_ + t];
#pragma unroll
  for (int k = 0; k < 3; ++k) {
    int j = gidx[i * 3 + k];
    float v = gvals[i * 3 + k];
    atomicAdd(&hidden3[(size_t)j * H_ + t], v * xs);
  }
  if (t == 0) {
#pragma unroll
    for (int k = 0; k < 3; ++k) atomicAdd(&colsum3[gidx[i * 3 + k]], gvals[i * 3 + k]);
  }
}

__global__ __launch_bounds__(128) void k_h3fin(float* __restrict__ hidden3,
      const float* __restrict__ hs, const float* __restrict__ colsum3,
      const float* __restrict__ diagv, float* __restrict__ rn3, int* __restrict__ keep2) {
  __shared__ float buf[128];
  int j = blockIdx.x, t = threadIdx.x;
  float v = hidden3[(size_t)j * H_ + t];
  if (colsum3[j] != 0.f) v += diagv[j] * hs[(size_t)j * H_ + t];
  hidden3[(size_t)j * H_ + t] = v;
  float ss = bred_sum128(v * v, buf);
  float sm = bred_sum128(v, buf);
  if (t == 0) {
    rn3[j] = (ss > 0.f) ? 1.f / sqrtf(ss) : 0.f;
    keep2[j] = (sm != 0.f) ? 1 : 0;
  }
}

// ---------------- attention prep: bf16 Qn/Kn, transposed V, keep as float ----------
__global__ __launch_bounds__(256) void k_prep_attn(const float* __restrict__ hs,
      const float* __restrict__ h3, const float* __restrict__ rqh,
      const float* __restrict__ rn3, const int* __restrict__ keep2,
      ushort* __restrict__ Qn, ushort* __restrict__ Kn, ushort* __restrict__ Vt,
      float* __restrict__ keepf) {
  __shared__ ushort T[H_][68];
  int t = threadIdx.x;
  int i0 = blockIdx.x * 64;
  int r = i0 + (t >> 2);
  int c0 = (t & 3) * 32;
  float rq = rqh[r], r3 = rn3[r];
  for (int c = c0; c < c0 + 32; c += 4) {
    float4 hv = *(const float4*)&hs[(size_t)r * H_ + c];
    float4 h3v = *(const float4*)&h3[(size_t)r * H_ + c];
    ushort q4[4] = {f2bf(hv.x * rq), f2bf(hv.y * rq), f2bf(hv.z * rq), f2bf(hv.w * rq)};
    ushort k4[4] = {f2bf(h3v.x * r3), f2bf(h3v.y * r3), f2bf(h3v.z * r3), f2bf(h3v.w * r3)};
    *(ushort4*)&Qn[(size_t)r * H_ + c] = *(ushort4*)q4;
    *(ushort4*)&Kn[(size_t)r * H_ + c] = *(ushort4*)k4;
    T[c + 0][r - i0] = f2bf(h3v.x);
    T[c + 1][r - i0] = f2bf(h3v.y);
    T[c + 2][r - i0] = f2bf(h3v.z);
    T[c + 3][r - i0] = f2bf(h3v.w);
  }
  if (t < 64) keepf[i0 + t] = (float)keep2[i0 + t];
  __syncthreads();
  int h = t >> 1, off = (t & 1) * 32;
  for (int u = 0; u < 32; u += 4) {
    ushort4 vv;
    vv.x = T[h][off + u]; vv.y = T[h][off + u + 1];
    vv.z = T[h][off + u + 2]; vv.w = T[h][off + u + 3];
    *(ushort4*)&Vt[(size_t)h * N_ + i0 + off + u] = vv;
  }
}

// ---------------- MFMA flash attention (j-split partials) ----------------
#define JSPLIT 8
__global__ __launch_bounds__(64) void k_attn_mfma(const ushort* __restrict__ Qn,
      const ushort* __restrict__ Kn, const ushort* __restrict__ Vt,
      const float* __restrict__ keepf, float* __restrict__ Opart,
      float* __restrict__ Mpart, float* __restrict__ Lpart) {
  __shared__ ushort Ps[32][72];
  int l = threadIdx.x;
  int lo16 = l & 15, hi = l >> 4;
  int i0 = blockIdx.x * 32;
  int sp = blockIdx.y;
  const int jspan = N_ / JSPLIT;

  bfrag aq[2][4];
#pragma unroll
  for (int mt = 0; mt < 2; ++mt)
#pragma unroll
    for (int kc = 0; kc < 4; ++kc)
      aq[mt][kc] = *(const bfrag*)&Qn[(size_t)(i0 + mt * 16 + lo16) * H_ + kc * 32 + hi * 8];

  f4 O[2][8];
#pragma unroll
  for (int mt = 0; mt < 2; ++mt)
#pragma unroll
    for (int ns = 0; ns < 8; ++ns) O[mt][ns] = (f4){0.f, 0.f, 0.f, 0.f};
  f4 m4[2], l4[2];
#pragma unroll
  for (int mt = 0; mt < 2; ++mt) {
    m4[mt] = (f4){-FLT_MAX, -FLT_MAX, -FLT_MAX, -FLT_MAX};
    l4[mt] = (f4){0.f, 0.f, 0.f, 0.f};
  }

  for (int jt = 0; jt < jspan / 64; ++jt) {
    int j0 = sp * jspan + jt * 64;
    float kp[4];
#pragma unroll
    for (int js = 0; js < 4; ++js) kp[js] = keepf[j0 + js * 16 + lo16];

#pragma unroll
    for (int mt = 0; mt < 2; ++mt) {
      f4 S[4];
#pragma unroll
      for (int js = 0; js < 4; ++js) {
        f4 acc = (f4){0.f, 0.f, 0.f, 0.f};
#pragma unroll
        for (int kc = 0; kc < 4; ++kc) {
          bfrag b = *(const bfrag*)&Kn[(size_t)(j0 + js * 16 + lo16) * H_ + kc * 32 + hi * 8];
          acc = __builtin_amdgcn_mfma_f32_16x16x32_bf16(aq[mt][kc], b, acc, 0, 0, 0);
        }
        S[js] = acc;
      }
      f4 Sm[4];
#pragma unroll
      for (int js = 0; js < 4; ++js)
#pragma unroll
        for (int r = 0; r < 4; ++r)
          Sm[js][r] = (kp[js] > 0.f) ? S[js][r] : -FLT_MAX;
      f4 tm;
#pragma unroll
      for (int r = 0; r < 4; ++r)
        tm[r] = fmaxf(fmaxf(Sm[0][r], Sm[1][r]), fmaxf(Sm[2][r], Sm[3][r]));
#pragma unroll
      for (int x = 1; x <= 8; x <<= 1)
#pragma unroll
        for (int r = 0; r < 4; ++r) tm[r] = fmaxf(tm[r], __shfl_xor(tm[r], x, 16));
      f4 nm, alpha;
#pragma unroll
      for (int r = 0; r < 4; ++r) {
        nm[r] = fmaxf(m4[mt][r], tm[r]);
        alpha[r] = expf(m4[mt][r] - nm[r]);
      }
      m4[mt] = nm;
      f4 ps = (f4){0.f, 0.f, 0.f, 0.f};
#pragma unroll
      for (int js = 0; js < 4; ++js)
#pragma unroll
        for (int r = 0; r < 4; ++r) {
          float p = kp[js] * expf(Sm[js][r] - nm[r]);
          ps[r] += p;
          Ps[mt * 16 + hi * 4 + r][js * 16 + lo16] = f2bf(p);
        }
#pragma unroll
      for (int x = 1; x <= 8; x <<= 1)
#pragma unroll
        for (int r = 0; r < 4; ++r) ps[r] += __shfl_xor(ps[r], x, 16);
#pragma unroll
      for (int r = 0; r < 4; ++r) l4[mt][r] = l4[mt][r] * alpha[r] + ps[r];
#pragma unroll
      for (int ns = 0; ns < 8; ++ns)
#pragma unroll
        for (int r = 0; r < 4; ++r) O[mt][ns][r] *= alpha[r];
    }
    __syncthreads();
#pragma unroll
    for (int kc = 0; kc < 2; ++kc) {
      bfrag ap0 = *(const bfrag*)&Ps[lo16][kc * 32 + hi * 8];
      bfrag ap1 = *(const bfrag*)&Ps[16 + lo16][kc * 32 + hi * 8];
#pragma unroll
      for (int ns = 0; ns < 8; ++ns) {
        bfrag bv = *(const bfrag*)&Vt[(size_t)(ns * 16 + lo16) * N_ + j0 + kc * 32 + hi * 8];
        O[0][ns] = __builtin_amdgcn_mfma_f32_16x16x32_bf16(ap0, bv, O[0][ns], 0, 0, 0);
        O[1][ns] = __builtin_amdgcn_mfma_f32_16x16x32_bf16(ap1, bv, O[1][ns], 0, 0, 0);
      }
    }
    __syncthreads();
  }
#pragma unroll
  for (int mt = 0; mt < 2; ++mt)
#pragma unroll
    for (int ns = 0; ns < 8; ++ns)
#pragma unroll
      for (int r = 0; r < 4; ++r) {
        int row = i0 + mt * 16 + hi * 4 + r;
        Opart[((size_t)sp * N_ + row) * H_ + ns * 16 + lo16] = O[mt][ns][r];
      }
  if (lo16 == 0) {
#pragma unroll
    for (int mt = 0; mt < 2; ++mt)
#pragma unroll
      for (int r = 0; r < 4; ++r) {
        size_t idx = (size_t)sp * N_ + i0 + mt * 16 + hi * 4 + r;
        Mpart[idx] = m4[mt][r];
        Lpart[idx] = l4[mt][r];
      }
  }
}

__global__ __launch_bounds__(128) void k_attn_merge(const float* __restrict__ Opart,
      const float* __restrict__ Mpart, const float* __restrict__ Lpart,
      float* __restrict__ outp) {
  int i = blockIdx.x, t = threadIdx.x;
  float mg = -FLT_MAX;
#pragma unroll
  for (int s = 0; s < JSPLIT; ++s) mg = fmaxf(mg, Mpart[(size_t)s * N_ + i]);
  float w[JSPLIT];
  float lg = 0.f;
#pragma unroll
  for (int s = 0; s < JSPLIT; ++s) {
    float ms = Mpart[(size_t)s * N_ + i];
    float ws = (mg > -0.5f * FLT_MAX) ? expf(ms - mg) : 0.f;
    w[s] = ws;
    lg += ws * Lpart[(size_t)s * N_ + i];
  }
  float inv = (lg > 0.f) ? 1.f / lg : 0.f;
  float acc = 0.f;
#pragma unroll
  for (int s = 0; s < JSPLIT; ++s)
    acc += w[s] * Opart[((size_t)s * N_ + i) * H_ + t];
  outp[(size_t)i * H_ + t] = acc * inv;
}

// ---------------- elementwise ----------------
__global__ __launch_bounds__(256) void k_sub2(const float4* __restrict__ a,
      const float4* __restrict__ b, float4* __restrict__ o) {
  int i = blockIdx.x * 256 + threadIdx.x;
  float4 x = a[i], y = b[i], r;
  r.x = x.x - y.x; r.y = x.y - y.y; r.z = x.z - y.z; r.w = x.w - y.w;
  o[i] = r;
}

__global__ __launch_bounds__(256) void k_sub3(const float4* __restrict__ a,
      const float4* __restrict__ b, const float4* __restrict__ c, float4* __restrict__ o) {
  int i = blockIdx.x * 256 + threadIdx.x;
  float4 x = a[i], y = b[i], z = c[i], r;
  r.x = x.x - y.x - z.x; r.y = x.y - y.y - z.y; r.z = x.z - y.z - z.z; r.w = x.w - y.w - z.w;
  o[i] = r;
}

__global__ __launch_bounds__(128) void k_pred(const float* __restrict__ a,
      const float* __restrict__ b, const float* __restrict__ c,
      const float* __restrict__ wout, const float* __restrict__ bout,
      float* __restrict__ outp) {
  __shared__ float buf[128];
  int i = blockIdx.x, t = threadIdx.x;
  size_t idx = (size_t)i * H_ + t;
  float v = (a[idx] + b[idx] + c[idx]) * wout[t];
  float s = bred_sum128(v, buf);
  if (t == 0) outp[i] = s + bout[0];
}

// ---------------- host ----------------
extern "C" void kernel_launch(void* const* d_in, const int* in_sizes, int n_in,
                              void* d_out, int out_size, void* d_ws, size_t ws_size,
                              hipStream_t stream) {
  const float* x          = (const float*)d_in[0];
  const float* mv         = (const float*)d_in[1];
  const int*   cm         = (const int*)d_in[2];
  const float* W_ps       = (const float*)d_in[3];
  const float* b_ps       = (const float*)d_in[4];
  const float* W_hs       = (const float*)d_in[5];
  const float* b_hs       = (const float*)d_in[6];
  const float* W_ps_fore  = (const float*)d_in[7];
  const float* b_ps_fore  = (const float*)d_in[8];
  const float* W_hs_fore  = (const float*)d_in[9];
  const float* b_hs_fore  = (const float*)d_in[10];
  const float* W_ps_back  = (const float*)d_in[11];
  const float* b_ps_back  = (const float*)d_in[12];
  const float* W_hs_back  = (const float*)d_in[13];
  const float* b_hs_back  = (const float*)d_in[14];
  const float* W_indi     = (const float*)d_in[15];
  const float* b_indi     = (const float*)d_in[16];
  const float* W_out      = (const float*)d_in[23];
  const float* b_out      = (const float*)d_in[24];
  float* outp = (float*)d_out;

  float* W = (float*)d_ws;
  const size_t NC = (size_t)N_ * C_;   // NC = 4*NH
  const size_t NH = (size_t)N_ * H_;
  const size_t CH = (size_t)C_ * H_;
  float* Sbuf = W;
  float* pback   = Sbuf;
  float* outps   = Sbuf + NH;
  float* hback   = Sbuf + 2 * NH;
  float* outindi = Sbuf + 3 * NH;
  size_t off = NC;
  float* T1       = W + off; off += NH;
  float* p_shared = W + off; off += NH;
  float* h_shared = W + off; off += NH;
  float* hidden3  = W + off; off += NH;
  float* h_info   = W + off; off += NH;
  float* out_hs   = W + off; off += NH;
  float* hidden1  = W + off; off += CH;
  float* hidden2  = W + off; off += CH;
  float* colsum1   = W + off; off += C_;
  float* colmax    = W + off; off += C_;
  float* colsumexp = W + off; off += C_;
  float* rny2      = W + off; off += C_;
  float* partb     = W + off; off += 32 * C_;
  float* rnx     = W + off; off += N_;
  float* rqh     = W + off; off += N_;
  float* diagv   = W + off; off += N_;
  float* colsum3 = W + off; off += N_;
  float* rn3     = W + off; off += N_;
  float* gvals   = W + off; off += 3 * N_;
  float* Mpart   = W + off; off += (size_t)JSPLIT * N_;
  float* Lpart   = W + off; off += (size_t)JSPLIT * N_;
  float* keepf   = W + off; off += N_;
  int* keep1 = (int*)(W + off); off += C_;
  int* keep2 = (int*)(W + off); off += N_;
  int* gidx  = (int*)(W + off); off += 3 * N_;
  ushort* Qn = (ushort*)(W + off); off += NH / 2;
  ushort* Kn = (ushort*)(W + off); off += NH / 2;
  ushort* Vt = (ushort*)(W + off); off += NH / 2;
  float* Opart = W + off; off += (size_t)JSPLIT * NH;   // stage-5 only
  // Gram scratch ALIASES Opart (stage-4 only; disjoint in time from attention):
  ushort* Ghi = (ushort*)Opart;                  // NH ushorts = NH/2 floats
  ushort* Glo = Ghi + NH;                        // next NH ushorts
  int*    Gip = (int*)(Opart + NH);              // GSPLIT*N*3 ints, well within Opart

  hipMemsetAsync(colsum1, 0, C_ * sizeof(float), stream);
  hipMemsetAsync(hidden1, 0, CH * sizeof(float), stream);
  hipMemsetAsync(hidden2, 0, CH * sizeof(float), stream);
  hipMemsetAsync(hidden3, 0, NH * sizeof(float), stream);
  hipMemsetAsync(colsum3, 0, N_ * sizeof(float), stream);

  // stage 1: market-value aggregation
  k_colsum1<<<dim3(2, 32), 256, 0, stream>>>(cm, mv, colsum1);
  k_agg<0><<<dim3(16, 8), 256, 0, stream>>>(x, cm, mv, nullptr, nullptr, hidden1);
  k_fin_hidden1<<<C_, 128, 0, stream>>>(hidden1, colsum1, keep1);
  k_rowstats<<<N_, 128, 0, stream>>>(x, rnx, nullptr, nullptr);

  // stage 2: softmax over stocks, hidden2
  k_gemm<1, 0><<<dim3(C_ / 64, N_ / 64), 256, 0, stream>>>(
      x, H_, hidden1, H_, Sbuf, C_, N_, C_, H_, nullptr, nullptr, nullptr);
  k_colmax_part<<<32, 256, 0, stream>>>(Sbuf, partb);
  k_colfin_max<<<1, 512, 0, stream>>>(partb, colmax);
  k_colsum_part<<<32, 256, 0, stream>>>(Sbuf, colmax, partb);
  k_colfin_sum<<<1, 512, 0, stream>>>(partb, colsumexp);
  k_agg<1><<<dim3(16, 8), 256, 0, stream>>>(x, nullptr, nullptr, Sbuf, colmax, hidden2);
  k_fin_hidden2<<<C_, 128, 0, stream>>>(hidden2, colsumexp, rny2);

  // stage 3: c2s softmax + p branch
  k_gemm<1, 0><<<dim3(C_ / 64, N_ / 64), 256, 0, stream>>>(
      x, H_, hidden2, H_, Sbuf, C_, N_, C_, H_, nullptr, rnx, rny2);
  k_rowsoftmax<<<N_, 256, 0, stream>>>(Sbuf, keep1);
  k_gemm<0, 0><<<dim3(H_ / 64, N_ / 64), 256, 0, stream>>>(
      Sbuf, C_, hidden2, H_, T1, H_, N_, H_, C_, nullptr, nullptr, nullptr);
  k_gemm<0, 0><<<dim3(2, 128), 256, 0, stream>>>(
      T1, H_, W_ps, H_, p_shared, H_, N_, H_, H_, b_ps, nullptr, nullptr);
  k_gemm<0, 0><<<dim3(2, 128), 256, 0, stream>>>(
      p_shared, H_, W_ps_back, H_, pback, H_, N_, H_, H_, b_ps_back, nullptr, nullptr);
  k_gemm<0, 1><<<dim3(2, 128), 256, 0, stream>>>(
      p_shared, H_, W_ps_fore, H_, outps, H_, N_, H_, H_, b_ps_fore, nullptr, nullptr);

  // stage 4: h_shared, N x N top-3 graph (MFMA candidates + exact rescore)
  k_sub2<<<NH / 4 / 256, 256, 0, stream>>>((const float4*)x, (const float4*)pback,
                                           (float4*)h_shared);
  k_rowstats<<<N_, 128, 0, stream>>>(h_shared, rqh, diagv, nullptr);
  k_prep_gram<<<N_ / 8, 256, 0, stream>>>(h_shared, rqh, Ghi, Glo);
  k_gram_mfma<<<dim3(N_ / 32, GSPLIT), 64, 0, stream>>>(Ghi, Glo, Gip);
  k_gram_rescore<<<N_ / 4, 256, 0, stream>>>(h_shared, rqh, Gip, gvals, gidx);
  k_scatter<<<N_, 128, 0, stream>>>(h_shared, gvals, gidx, hidden3, colsum3);
  k_h3fin<<<N_, 128, 0, stream>>>(hidden3, h_shared, colsum3, diagv, rn3, keep2);

  // stage 5: MFMA flash attention, h branch
  k_prep_attn<<<N_ / 64, 256, 0, stream>>>(h_shared, hidden3, rqh, rn3, keep2,
                                           Qn, Kn, Vt, keepf);
  k_attn_mfma<<<dim3(N_ / 32, JSPLIT), 64, 0, stream>>>(Qn, Kn, Vt, keepf,
                                                        Opart, Mpart, Lpart);
  k_attn_merge<<<N_, 128, 0, stream>>>(Opart, Mpart, Lpart, T1);
  k_gemm<0, 0><<<dim3(2, 128), 256, 0, stream>>>(
      T1, H_, W_hs, H_, h_info, H_, N_, H_, H_, b_hs, nullptr, nullptr);
  k_gemm<0, 0><<<dim3(2, 128), 256, 0, stream>>>(
      h_info, H_, W_hs_back, H_, hback, H_, N_, H_, H_, b_hs_back, nullptr, nullptr);
  k_gemm<0, 1><<<dim3(2, 128), 256, 0, stream>>>(
      h_info, H_, W_hs_fore, H_, out_hs, H_, N_, H_, H_, b_hs_fore, nullptr, nullptr);

  // stage 6: individual branch + final projection
  k_sub3<<<NH / 4 / 256, 256, 0, stream>>>((const float4*)x, (const float4*)pback,
                                           (const float4*)hback, (float4*)h_shared);
  k_gemm<0, 1><<<dim3(2, 128), 256, 0, stream>>>(
      h_shared, H_, W_indi, H_, outindi, H_, N_, H_, H_, b_indi, nullptr, nullptr);
  k_pred<<<N_, 128, 0, stream>>>(outps, out_hs, outindi, W_out, b_out, outp);
}